// Round 1
// baseline (1173.383 us; speedup 1.0000x reference)
//
#include <hip/hip_runtime.h>

#define NN 20000
#define EE 320000
#define BB 64

typedef _Float16 half8 __attribute__((ext_vector_type(8)));
typedef float floatx4 __attribute__((ext_vector_type(4)));

// ---------------- prep: weight folding ----------------
// Wp[k][j] = sum_t edge_W[k][t]*We[t][j]  (k<63); row 63 = sum_t edge_b[t]*We[t][j]
__global__ void k_prep_edgeW(const float* __restrict__ edge_W, const float* __restrict__ edge_b,
                             const float* __restrict__ We0, const float* __restrict__ We1,
                             float* __restrict__ Wp0, float* __restrict__ Wp1) {
    __shared__ float row[256];
    int k = blockIdx.x, layer = blockIdx.y, j = threadIdx.x;
    row[j] = (k < 63) ? edge_W[k*256 + j] : edge_b[j];
    __syncthreads();
    const float* We = layer ? We1 : We0;
    float acc = 0.f;
    for (int t = 0; t < 256; ++t) acc += row[t] * We[t*256 + j];
    (layer ? Wp1 : Wp0)[k*256 + j] = acc;
}

// Acat[k][j] (k<5) = sum_d node_W[k][d] * {Wl0|Wr0}[d][j];  row 5 adds node_b path + bl0/br0
__global__ void k_prep_acat(const float* __restrict__ node_W, const float* __restrict__ node_b,
                            const float* __restrict__ Wl0, const float* __restrict__ bl0,
                            const float* __restrict__ Wr0, const float* __restrict__ br0,
                            float* __restrict__ Acat) {
    __shared__ float row[256];
    int k = blockIdx.x, j = threadIdx.x;
    if (j < 256) row[j] = (k < 5) ? node_W[k*256 + j] : node_b[j];
    __syncthreads();
    int jj = j & 255;
    const float* W = (j < 256) ? Wl0 : Wr0;
    float acc = 0.f;
    for (int t = 0; t < 256; ++t) acc += row[t] * W[t*256 + jj];
    if (k == 5) acc += (j < 256) ? bl0[jj] : br0[jj];
    Acat[k*512 + j] = acc;
}

// transpose+fp16: WlWr1t [512][256], blr1[512], mlpWt [64][256]
__global__ void k_prep_t16(const float* __restrict__ Wl1, const float* __restrict__ bl1,
                           const float* __restrict__ Wr1, const float* __restrict__ br1,
                           const float* __restrict__ mlp_W,
                           _Float16* __restrict__ WlWr1t, float* __restrict__ blr1,
                           _Float16* __restrict__ mlpWt) {
    int n = blockIdx.x, k = threadIdx.x;
    if (n < 512) {
        float v = (n < 256) ? Wl1[k*256 + n] : Wr1[k*256 + (n - 256)];
        WlWr1t[n*256 + k] = (_Float16)v;
        if (k == 0) blr1[n] = (n < 256) ? bl1[n] : br1[n - 256];
    } else {
        int nn = n - 512;
        mlpWt[nn*256 + k] = (_Float16)mlp_W[k*64 + nn];
    }
}

// ---------------- CSR by dst ----------------
__global__ void k_hist(const int* __restrict__ ei, int* __restrict__ counts) {
    int e = blockIdx.x*256 + threadIdx.x;
    if (e < EE) atomicAdd(&counts[ei[EE + e]], 1);
}

__global__ __launch_bounds__(1024) void k_scan(const int* __restrict__ counts,
                                               int* __restrict__ row_ptr, int* __restrict__ cursor) {
    __shared__ int part[1024];
    int t = threadIdx.x;
    const int per = (NN + 1023) / 1024;
    int b0 = t*per, b1 = min(b0 + per, NN);
    int s = 0;
    for (int i = b0; i < b1; ++i) s += counts[i];
    part[t] = s; __syncthreads();
    for (int d = 1; d < 1024; d <<= 1) {
        int v = (t >= d) ? part[t-d] : 0;
        __syncthreads();
        part[t] += v;
        __syncthreads();
    }
    int run = (t == 0) ? 0 : part[t-1];
    for (int i = b0; i < b1; ++i) { row_ptr[i] = run; cursor[i] = run; run += counts[i]; }
    if (t == 0) row_ptr[NN] = EE;
}

__global__ void k_scatter(const int* __restrict__ ei, int* __restrict__ cursor,
                          int* __restrict__ eid, int* __restrict__ csr_src) {
    int e = blockIdx.x*256 + threadIdx.x;
    if (e < EE) {
        int d = ei[EE + e];
        int p = atomicAdd(&cursor[d], 1);
        eid[p] = e;
        csr_src[p] = ei[e];
    }
}

// ---------------- layer 0 xl/xr via folded K=5 ----------------
__global__ void k_xlxr0(const float* __restrict__ x, const float* __restrict__ Acat,
                        float* __restrict__ xlxr) {
    int n = blockIdx.x, j = threadIdx.x;
    float a0 = Acat[5*512 + j], a1 = Acat[5*512 + 256 + j];
#pragma unroll
    for (int k = 0; k < 5; ++k) {
        float xv = x[n*5 + k];
        a0 += xv * Acat[k*512 + j];
        a1 += xv * Acat[k*512 + 256 + j];
    }
    xlxr[(size_t)n*512 + j] = a0;
    xlxr[(size_t)n*512 + 256 + j] = a1;
}

// ---------------- per-edge alpha (fused ee = attr @ Wp) ----------------
__global__ __launch_bounds__(256) void k_alpha(const float* __restrict__ attr, const int* __restrict__ ei,
                        const float* __restrict__ Wp, const float* __restrict__ att,
                        const float* __restrict__ xlxr, float* __restrict__ alpha) {
    __shared__ float sattr[8][64];
    int j = threadIdx.x;
    int h = j >> 6;
    float w[64];
#pragma unroll
    for (int k = 0; k < 63; ++k) w[k] = Wp[k*256 + j];
    w[63] = 0.f;
    float be = Wp[63*256 + j];
    float aj = att[j];
    const int nchunk = EE / 8;
    for (int ch = blockIdx.x; ch < nchunk; ch += gridDim.x) {
        int base = ch * 8;
        if (j < 64) {
#pragma unroll
            for (int i = 0; i < 8; ++i)
                sattr[i][j] = (j < 63) ? attr[(size_t)(base + i)*63 + j] : 0.f;
        }
        __syncthreads();
#pragma unroll 1
        for (int i = 0; i < 8; ++i) {
            int e = base + i;
            int s = ei[e], d = ei[EE + e];
            float acc = be;
            const float4* sp = (const float4*)sattr[i];
#pragma unroll
            for (int k4 = 0; k4 < 16; ++k4) {
                float4 av = sp[k4];
                acc += av.x*w[4*k4+0] + av.y*w[4*k4+1] + av.z*w[4*k4+2] + av.w*w[4*k4+3];
            }
            acc += xlxr[(size_t)s*512 + j] + xlxr[(size_t)d*512 + 256 + j];
            float lr = (acc > 0.f) ? acc : 0.2f*acc;
            float v = lr * aj;
#pragma unroll
            for (int m = 1; m < 64; m <<= 1) v += __shfl_xor(v, m);
            if ((j & 63) == 0) alpha[(size_t)e*4 + h] = v;
        }
        __syncthreads();
    }
}

// ---------------- per-dst softmax + aggregate ----------------
__global__ __launch_bounds__(256) void k_agg(const float* __restrict__ alpha, const int* __restrict__ eid,
                      const int* __restrict__ csr_src, const int* __restrict__ row_ptr,
                      const float* __restrict__ xlxr, const float* __restrict__ bias,
                      float* __restrict__ gat) {
    int n = blockIdx.x, j = threadIdx.x;
    int h = j >> 6, lane = j & 63;
    int s = row_ptr[n], e = row_ptr[n+1];
    if (e <= s) { gat[(size_t)n*256 + j] = bias[j]; return; }
    float mx = -3.0e38f;
    for (int p = s + lane; p < e; p += 64) mx = fmaxf(mx, alpha[(size_t)eid[p]*4 + h]);
#pragma unroll
    for (int m = 1; m < 64; m <<= 1) mx = fmaxf(mx, __shfl_xor(mx, m));
    float sm = 0.f;
    for (int p = s + lane; p < e; p += 64) sm += __expf(alpha[(size_t)eid[p]*4 + h] - mx);
#pragma unroll
    for (int m = 1; m < 64; m <<= 1) sm += __shfl_xor(sm, m);
    float rden = 1.0f / sm;
    float acc = 0.f;
    for (int p = s; p < e; ++p) {
        float wgt = __expf(alpha[(size_t)eid[p]*4 + h] - mx) * rden;
        acc += wgt * xlxr[(size_t)csr_src[p]*512 + j];
    }
    gat[(size_t)n*256 + j] = acc + bias[j];
}

// ---------------- batchnorm ----------------
__global__ void k_bn_stats(const float* __restrict__ X, float* __restrict__ stats) {
    int j = threadIdx.x;
    float s = 0.f, q = 0.f;
    for (int r = blockIdx.x; r < NN; r += gridDim.x) {
        float v = X[(size_t)r*256 + j];
        s += v; q += v*v;
    }
    atomicAdd(&stats[j], s);
    atomicAdd(&stats[256 + j], q);
}

__global__ void k_bn_final(const float* __restrict__ stats, const float* __restrict__ gamma,
                           const float* __restrict__ beta, float* __restrict__ ss) {
    int j = threadIdx.x;
    float mean = stats[j] * (1.0f/NN);
    float var  = stats[256 + j] * (1.0f/NN) - mean*mean;
    float sc = rsqrtf(var + 1e-5f) * gamma[j];
    ss[j] = sc;
    ss[256 + j] = beta[j] - mean*sc;
}

__global__ void k_bn_apply(const float* __restrict__ X, const float* __restrict__ ss,
                           _Float16* __restrict__ Hh) {
    size_t idx = (size_t)blockIdx.x*256 + threadIdx.x;
    int col = threadIdx.x;  // rows are 256 wide, blockDim=256
    float v = X[idx]*ss[col] + ss[256+col];
    Hh[idx] = (_Float16)fmaxf(v, 0.f);
}

// ---------------- fp16 MFMA GEMM: C[M,cols] = A[M,K] @ Bt[N,K]^T + bias ----------------
template<bool RELU>
__global__ __launch_bounds__(256) void k_gemm(const _Float16* __restrict__ A, const _Float16* __restrict__ Bt,
                       const float* __restrict__ bias, float* __restrict__ C,
                       int M, int K, int ldc) {
    __shared__ __align__(16) _Float16 As[128][72];
    __shared__ __align__(16) _Float16 Bs[64][72];
    int tid = threadIdx.x;
    int wave = tid >> 6, lane = tid & 63;
    int l15 = lane & 15, l4 = lane >> 4;
    int row0 = blockIdx.x*128, n0 = blockIdx.y*64;
    floatx4 acc[2][4] = {};
    for (int k0 = 0; k0 < K; k0 += 64) {
#pragma unroll
        for (int q = 0; q < 4; ++q) {
            int c = tid + q*256;
            int r = c >> 3, kc = (c & 7)*8;
            int gr = row0 + r; if (gr >= M) gr = M - 1;
            *(half8*)&As[r][kc] = *(const half8*)&A[(size_t)gr*K + k0 + kc];
        }
#pragma unroll
        for (int q = 0; q < 2; ++q) {
            int c = tid + q*256;
            int r = c >> 3, kc = (c & 7)*8;
            *(half8*)&Bs[r][kc] = *(const half8*)&Bt[(size_t)(n0 + r)*K + k0 + kc];
        }
        __syncthreads();
#pragma unroll
        for (int ks = 0; ks < 64; ks += 32) {
            half8 a0 = *(const half8*)&As[wave*32 + l15][ks + l4*8];
            half8 a1 = *(const half8*)&As[wave*32 + 16 + l15][ks + l4*8];
#pragma unroll
            for (int nb = 0; nb < 4; ++nb) {
                half8 b = *(const half8*)&Bs[nb*16 + l15][ks + l4*8];
                acc[0][nb] = __builtin_amdgcn_mfma_f32_16x16x32_f16(a0, b, acc[0][nb], 0, 0, 0);
                acc[1][nb] = __builtin_amdgcn_mfma_f32_16x16x32_f16(a1, b, acc[1][nb], 0, 0, 0);
            }
        }
        __syncthreads();
    }
#pragma unroll
    for (int m = 0; m < 2; ++m)
#pragma unroll
    for (int nb = 0; nb < 4; ++nb) {
        int col = n0 + nb*16 + l15;
        float bv = bias[col];
#pragma unroll
        for (int r = 0; r < 4; ++r) {
            int grow = row0 + wave*32 + m*16 + l4*4 + r;
            if (grow < M) {
                float v = acc[m][nb][r] + bv;
                if (RELU) v = fmaxf(v, 0.f);
                C[(size_t)grow*ldc + col] = v;
            }
        }
    }
}

// ---------------- pooling + output ----------------
__global__ void k_pool(const float* __restrict__ mo, const int* __restrict__ batch,
                       float* __restrict__ pooled, float* __restrict__ pcnt) {
    int idx = blockIdx.x*256 + threadIdx.x;
    if (idx >= NN*64) return;
    int n = idx >> 6, j = idx & 63;
    int b = batch[n];
    atomicAdd(&pooled[b*64 + j], mo[idx]);
    if (j == 0) atomicAdd(&pcnt[b], 1.0f);
}

__global__ void k_final(const float* __restrict__ pooled, const float* __restrict__ pcnt,
                        const float* __restrict__ outW, const float* __restrict__ outb,
                        float* __restrict__ out) {
    int t = threadIdx.x;
    if (t >= 320) return;
    int b = t / 5, c = t % 5;
    float rc = 1.f / fmaxf(pcnt[b], 1.f);
    float acc = outb[c];
    for (int k = 0; k < 64; ++k) acc += pooled[b*64 + k] * rc * outW[k*5 + c];
    out[t] = acc;
}

extern "C" void kernel_launch(void* const* d_in, const int* in_sizes, int n_in,
                              void* d_out, int out_size, void* d_ws, size_t ws_size,
                              hipStream_t stream) {
    const float* x      = (const float*)d_in[0];
    const int*   ei     = (const int*)d_in[1];
    const float* attr   = (const float*)d_in[2];
    const int*   batch  = (const int*)d_in[3];
    const float* node_W = (const float*)d_in[4];
    const float* node_b = (const float*)d_in[5];
    const float* edge_W = (const float*)d_in[6];
    const float* edge_b = (const float*)d_in[7];
    const float* Wl[2]   = {(const float*)d_in[8],  (const float*)d_in[17]};
    const float* bl[2]   = {(const float*)d_in[9],  (const float*)d_in[18]};
    const float* Wr[2]   = {(const float*)d_in[10], (const float*)d_in[19]};
    const float* br[2]   = {(const float*)d_in[11], (const float*)d_in[20]};
    const float* We[2]   = {(const float*)d_in[12], (const float*)d_in[21]};
    const float* att[2]  = {(const float*)d_in[13], (const float*)d_in[22]};
    const float* bias[2] = {(const float*)d_in[14], (const float*)d_in[23]};
    const float* gamma[2]= {(const float*)d_in[15], (const float*)d_in[24]};
    const float* beta[2] = {(const float*)d_in[16], (const float*)d_in[25]};
    const float* mlp_W = (const float*)d_in[26];
    const float* mlp_b = (const float*)d_in[27];
    const float* out_W = (const float*)d_in[28];
    const float* out_b = (const float*)d_in[29];
    float* out = (float*)d_out;

    char* p = (char*)d_ws;
    size_t off = 0;
    auto carve = [&](size_t bytes) -> void* {
        void* r = p + off;
        off = (off + bytes + 255) & ~(size_t)255;
        return r;
    };
    float*    Wp0    = (float*)carve(64*256*4);
    float*    Wp1    = (float*)carve(64*256*4);
    float*    Acat   = (float*)carve(6*512*4);
    _Float16* WlWr1t = (_Float16*)carve(512*256*2);
    float*    blr1   = (float*)carve(512*4);
    _Float16* mlpWt  = (_Float16*)carve(64*256*2);
    float*    ss     = (float*)carve(512*4);
    float*    xlxr   = (float*)carve((size_t)NN*512*4);
    float*    gat    = (float*)carve((size_t)NN*256*4);
    _Float16* h16    = (_Float16*)carve((size_t)NN*256*2);
    float*    alpha  = (float*)carve((size_t)EE*4*4);
    float*    mlo    = (float*)carve((size_t)NN*64*4);
    int*      row_ptr= (int*)carve((NN+1)*4);
    int*      eid    = (int*)carve((size_t)EE*4);
    int*      csrc   = (int*)carve((size_t)EE*4);
    int*      cursor = (int*)carve(NN*4);
    char*     zz     = (char*)carve((NN + 1024 + 4096 + 64)*4);
    int*      counts = (int*)zz;
    float*    stats  = (float*)(zz + (size_t)NN*4);
    float*    pooled = (float*)(zz + (size_t)(NN+1024)*4);
    float*    pcnt   = (float*)(zz + (size_t)(NN+1024+4096)*4);
    if (off > ws_size) return;  // workspace too small: bail (output stays wrong -> visible signal)

    hipMemsetAsync(zz, 0, (size_t)(NN + 1024 + 4096 + 64)*4, stream);
    k_prep_edgeW<<<dim3(64,2), 256, 0, stream>>>(edge_W, edge_b, We[0], We[1], Wp0, Wp1);
    k_prep_acat<<<6, 512, 0, stream>>>(node_W, node_b, Wl[0], bl[0], Wr[0], br[0], Acat);
    k_prep_t16<<<576, 256, 0, stream>>>(Wl[1], bl[1], Wr[1], br[1], mlp_W, WlWr1t, blr1, mlpWt);
    k_hist<<<(EE+255)/256, 256, 0, stream>>>(ei, counts);
    k_scan<<<1, 1024, 0, stream>>>(counts, row_ptr, cursor);
    k_scatter<<<(EE+255)/256, 256, 0, stream>>>(ei, cursor, eid, csrc);
    k_xlxr0<<<NN, 256, 0, stream>>>(x, Acat, xlxr);

    for (int L = 0; L < 2; ++L) {
        k_alpha<<<4096, 256, 0, stream>>>(attr, ei, L ? Wp1 : Wp0, att[L], xlxr, alpha);
        k_agg<<<NN, 256, 0, stream>>>(alpha, eid, csrc, row_ptr, xlxr, bias[L], gat);
        k_bn_stats<<<256, 256, 0, stream>>>(gat, stats + L*512);
        k_bn_final<<<1, 256, 0, stream>>>(stats + L*512, gamma[L], beta[L], ss);
        k_bn_apply<<<NN, 256, 0, stream>>>(gat, ss, h16);
        if (L == 0)
            k_gemm<false><<<dim3(157, 8), 256, 0, stream>>>(h16, WlWr1t, blr1, xlxr, NN, 256, 512);
        else
            k_gemm<true><<<dim3(157, 1), 256, 0, stream>>>(h16, mlpWt, mlp_b, mlo, NN, 256, 64);
    }
    k_pool<<<(NN*64+255)/256, 256, 0, stream>>>(mlo, batch, pooled, pcnt);
    k_final<<<1, 320, 0, stream>>>(pooled, pcnt, out_W, out_b, out);
}

// Round 2
// 716.714 us; speedup vs baseline: 1.6372x; 1.6372x over previous
//
#include <hip/hip_runtime.h>

#define NN 20000
#define EE 320000
#define BB 64

typedef _Float16 half8 __attribute__((ext_vector_type(8)));
typedef float floatx4 __attribute__((ext_vector_type(4)));

// ---------------- prep: weight folding ----------------
// Wpt[layer][j*64+k] = fp16( sum_t edge_W[k][t]*We[t][j] ) for k<63; k=63 row = edge_b@We (bias)
__global__ void k_prep_edgeW(const float* __restrict__ edge_W, const float* __restrict__ edge_b,
                             const float* __restrict__ We0, const float* __restrict__ We1,
                             _Float16* __restrict__ Wpt0, _Float16* __restrict__ Wpt1) {
    __shared__ float row[256];
    int k = blockIdx.x, layer = blockIdx.y, j = threadIdx.x;
    row[j] = (k < 63) ? edge_W[k*256 + j] : edge_b[j];
    __syncthreads();
    const float* We = layer ? We1 : We0;
    float acc = 0.f;
    for (int t = 0; t < 256; ++t) acc += row[t] * We[t*256 + j];
    (layer ? Wpt1 : Wpt0)[j*64 + k] = (_Float16)acc;   // transposed [col][k] fp16
}

// Acat[k][j] (k<5) = sum_d node_W[k][d] * {Wl0|Wr0}[d][j];  row 5 adds node_b path + bl0/br0
__global__ void k_prep_acat(const float* __restrict__ node_W, const float* __restrict__ node_b,
                            const float* __restrict__ Wl0, const float* __restrict__ bl0,
                            const float* __restrict__ Wr0, const float* __restrict__ br0,
                            float* __restrict__ Acat) {
    __shared__ float row[256];
    int k = blockIdx.x, j = threadIdx.x;
    if (j < 256) row[j] = (k < 5) ? node_W[k*256 + j] : node_b[j];
    __syncthreads();
    int jj = j & 255;
    const float* W = (j < 256) ? Wl0 : Wr0;
    float acc = 0.f;
    for (int t = 0; t < 256; ++t) acc += row[t] * W[t*256 + jj];
    if (k == 5) acc += (j < 256) ? bl0[jj] : br0[jj];
    Acat[k*512 + j] = acc;
}

// transpose+fp16: WlWr1t [512][256], blr1[512], mlpWt [64][256]
__global__ void k_prep_t16(const float* __restrict__ Wl1, const float* __restrict__ bl1,
                           const float* __restrict__ Wr1, const float* __restrict__ br1,
                           const float* __restrict__ mlp_W,
                           _Float16* __restrict__ WlWr1t, float* __restrict__ blr1,
                           _Float16* __restrict__ mlpWt) {
    int n = blockIdx.x, k = threadIdx.x;
    if (n < 512) {
        float v = (n < 256) ? Wl1[k*256 + n] : Wr1[k*256 + (n - 256)];
        WlWr1t[n*256 + k] = (_Float16)v;
        if (k == 0) blr1[n] = (n < 256) ? bl1[n] : br1[n - 256];
    } else {
        int nn = n - 512;
        mlpWt[nn*256 + k] = (_Float16)mlp_W[k*64 + nn];
    }
}

// ---------------- CSR by dst ----------------
__global__ void k_hist(const int* __restrict__ ei, int* __restrict__ counts) {
    int e = blockIdx.x*256 + threadIdx.x;
    if (e < EE) atomicAdd(&counts[ei[EE + e]], 1);
}

__global__ __launch_bounds__(1024) void k_scan(const int* __restrict__ counts,
                                               int* __restrict__ row_ptr, int* __restrict__ cursor) {
    __shared__ int part[1024];
    int t = threadIdx.x;
    const int per = (NN + 1023) / 1024;
    int b0 = t*per, b1 = min(b0 + per, NN);
    int s = 0;
    for (int i = b0; i < b1; ++i) s += counts[i];
    part[t] = s; __syncthreads();
    for (int d = 1; d < 1024; d <<= 1) {
        int v = (t >= d) ? part[t-d] : 0;
        __syncthreads();
        part[t] += v;
        __syncthreads();
    }
    int run = (t == 0) ? 0 : part[t-1];
    for (int i = b0; i < b1; ++i) { row_ptr[i] = run; cursor[i] = run; run += counts[i]; }
    if (t == 0) row_ptr[NN] = EE;
}

__global__ void k_scatter(const int* __restrict__ ei, int* __restrict__ cursor,
                          int* __restrict__ eid, int* __restrict__ csr_src) {
    int e = blockIdx.x*256 + threadIdx.x;
    if (e < EE) {
        int d = ei[EE + e];
        int p = atomicAdd(&cursor[d], 1);
        eid[p] = e;
        csr_src[p] = ei[e];
    }
}

// ---------------- layer 0 xl/xr via folded K=5 ----------------
__global__ void k_xlxr0(const float* __restrict__ x, const float* __restrict__ Acat,
                        float* __restrict__ xlxr) {
    int n = blockIdx.x, j = threadIdx.x;
    float a0 = Acat[5*512 + j], a1 = Acat[5*512 + 256 + j];
#pragma unroll
    for (int k = 0; k < 5; ++k) {
        float xv = x[n*5 + k];
        a0 += xv * Acat[k*512 + j];
        a1 += xv * Acat[k*512 + 256 + j];
    }
    xlxr[(size_t)n*512 + j] = a0;
    xlxr[(size_t)n*512 + 256 + j] = a1;
}

// ---------------- per-edge alpha: MFMA ee + register phase-B ----------------
// wave w handles head w (cols w*64 .. w*64+63). 64 edges per chunk.
__global__ __launch_bounds__(256) void k_alpha2(const float* __restrict__ attr,
        const int* __restrict__ ei, const _Float16* __restrict__ Wpt,
        const float* __restrict__ att, const float* __restrict__ xlxr,
        float* __restrict__ alpha) {
    __shared__ _Float16 As[64*72];           // [edge][k] padded to 72
    __shared__ int ssrc[64], sdst[64];
    int tid = threadIdx.x;
    int wave = tid >> 6, lane = tid & 63;
    int l15 = lane & 15, l4 = lane >> 4;

    // hoist B-fragments (Wpt[col][k]) + att into registers: chunk-invariant
    half8 bf[4][2];
    float attv[4];
#pragma unroll
    for (int ct = 0; ct < 4; ++ct) {
        int col = wave*64 + ct*16 + l15;
        attv[ct] = att[col];
#pragma unroll
        for (int ks = 0; ks < 2; ++ks)
            bf[ct][ks] = *(const half8*)&Wpt[(size_t)col*64 + ks*32 + l4*8];
    }

    int row = tid >> 2, cq = tid & 3;
    for (int ch = blockIdx.x; ch < EE/64; ch += gridDim.x) {
        int e0 = ch * 64;
        // stage attr fp32->fp16 (k=63 -> 1.0 bias lane), and src/dst ids
        {
            const float* ap = attr + (size_t)(e0 + row)*63 + cq*16;
            _Float16 t16[16];
#pragma unroll
            for (int i = 0; i < 16; ++i) {
                int k = cq*16 + i;
                t16[i] = (k < 63) ? (_Float16)ap[i] : ((k == 63) ? (_Float16)1.0f : (_Float16)0.0f);
            }
            *(half8*)&As[row*72 + cq*16]     = *(const half8*)&t16[0];
            *(half8*)&As[row*72 + cq*16 + 8] = *(const half8*)&t16[8];
            if (tid < 64) ssrc[tid] = ei[e0 + tid];
            else if (tid < 128) sdst[tid - 64] = ei[EE + e0 + tid - 64];
        }
        __syncthreads();
#pragma unroll
        for (int et = 0; et < 4; ++et) {
            half8 a0 = *(const half8*)&As[(et*16 + l15)*72 + l4*8];
            half8 a1 = *(const half8*)&As[(et*16 + l15)*72 + 32 + l4*8];
            floatx4 acc[4];
#pragma unroll
            for (int ct = 0; ct < 4; ++ct) {
                floatx4 z = {};
                acc[ct] = __builtin_amdgcn_mfma_f32_16x16x32_f16(a0, bf[ct][0], z, 0, 0, 0);
                acc[ct] = __builtin_amdgcn_mfma_f32_16x16x32_f16(a1, bf[ct][1], acc[ct], 0, 0, 0);
            }
            int4 sv = *(const int4*)&ssrc[et*16 + l4*4];
            int4 dv = *(const int4*)&sdst[et*16 + l4*4];
            int se[4] = {sv.x, sv.y, sv.z, sv.w};
            int de[4] = {dv.x, dv.y, dv.z, dv.w};
#pragma unroll
            for (int r = 0; r < 4; ++r) {
                const float* xp = xlxr + (size_t)se[r]*512 + wave*64 + l15;
                const float* rp = xlxr + (size_t)de[r]*512 + 256 + wave*64 + l15;
                float p = 0.f;
#pragma unroll
                for (int ct = 0; ct < 4; ++ct) {
                    float m = acc[ct][r] + xp[ct*16] + rp[ct*16];
                    float lr = (m > 0.f) ? m : 0.2f*m;
                    p += lr * attv[ct];
                }
                p += __shfl_xor(p, 1);
                p += __shfl_xor(p, 2);
                p += __shfl_xor(p, 4);
                p += __shfl_xor(p, 8);
                if (l15 == 0) alpha[(size_t)(e0 + et*16 + l4*4 + r)*4 + wave] = p;
            }
        }
        __syncthreads();
    }
}

// ---------------- per-dst softmax + aggregate ----------------
__global__ __launch_bounds__(256) void k_agg(const float* __restrict__ alpha, const int* __restrict__ eid,
                      const int* __restrict__ csr_src, const int* __restrict__ row_ptr,
                      const float* __restrict__ xlxr, const float* __restrict__ bias,
                      float* __restrict__ gat) {
    int n = blockIdx.x, j = threadIdx.x;
    int h = j >> 6, lane = j & 63;
    int s = row_ptr[n], e = row_ptr[n+1];
    if (e <= s) { gat[(size_t)n*256 + j] = bias[j]; return; }
    float mx = -3.0e38f;
    for (int p = s + lane; p < e; p += 64) mx = fmaxf(mx, alpha[(size_t)eid[p]*4 + h]);
#pragma unroll
    for (int m = 1; m < 64; m <<= 1) mx = fmaxf(mx, __shfl_xor(mx, m));
    float sm = 0.f;
    for (int p = s + lane; p < e; p += 64) sm += __expf(alpha[(size_t)eid[p]*4 + h] - mx);
#pragma unroll
    for (int m = 1; m < 64; m <<= 1) sm += __shfl_xor(sm, m);
    float rden = 1.0f / sm;
    float acc = 0.f;
    for (int p = s; p < e; ++p) {
        float wgt = __expf(alpha[(size_t)eid[p]*4 + h] - mx) * rden;
        acc += wgt * xlxr[(size_t)csr_src[p]*512 + j];
    }
    gat[(size_t)n*256 + j] = acc + bias[j];
}

// ---------------- batchnorm ----------------
__global__ void k_bn_stats(const float* __restrict__ X, float* __restrict__ stats) {
    int j = threadIdx.x;
    float s = 0.f, q = 0.f;
    for (int r = blockIdx.x; r < NN; r += gridDim.x) {
        float v = X[(size_t)r*256 + j];
        s += v; q += v*v;
    }
    atomicAdd(&stats[j], s);
    atomicAdd(&stats[256 + j], q);
}

__global__ void k_bn_final(const float* __restrict__ stats, const float* __restrict__ gamma,
                           const float* __restrict__ beta, float* __restrict__ ss) {
    int j = threadIdx.x;
    float mean = stats[j] * (1.0f/NN);
    float var  = stats[256 + j] * (1.0f/NN) - mean*mean;
    float sc = rsqrtf(var + 1e-5f) * gamma[j];
    ss[j] = sc;
    ss[256 + j] = beta[j] - mean*sc;
}

__global__ void k_bn_apply(const float* __restrict__ X, const float* __restrict__ ss,
                           _Float16* __restrict__ Hh) {
    size_t idx = (size_t)blockIdx.x*256 + threadIdx.x;
    int col = threadIdx.x;  // rows are 256 wide, blockDim=256
    float v = X[idx]*ss[col] + ss[256+col];
    Hh[idx] = (_Float16)fmaxf(v, 0.f);
}

// ---------------- fp16 MFMA GEMM: C[M,cols] = A[M,K] @ Bt[N,K]^T + bias ----------------
template<bool RELU>
__global__ __launch_bounds__(256) void k_gemm(const _Float16* __restrict__ A, const _Float16* __restrict__ Bt,
                       const float* __restrict__ bias, float* __restrict__ C,
                       int M, int K, int ldc) {
    __shared__ __align__(16) _Float16 As[128][72];
    __shared__ __align__(16) _Float16 Bs[64][72];
    int tid = threadIdx.x;
    int wave = tid >> 6, lane = tid & 63;
    int l15 = lane & 15, l4 = lane >> 4;
    int row0 = blockIdx.x*128, n0 = blockIdx.y*64;
    floatx4 acc[2][4] = {};
    for (int k0 = 0; k0 < K; k0 += 64) {
#pragma unroll
        for (int q = 0; q < 4; ++q) {
            int c = tid + q*256;
            int r = c >> 3, kc = (c & 7)*8;
            int gr = row0 + r; if (gr >= M) gr = M - 1;
            *(half8*)&As[r][kc] = *(const half8*)&A[(size_t)gr*K + k0 + kc];
        }
#pragma unroll
        for (int q = 0; q < 2; ++q) {
            int c = tid + q*256;
            int r = c >> 3, kc = (c & 7)*8;
            *(half8*)&Bs[r][kc] = *(const half8*)&Bt[(size_t)(n0 + r)*K + k0 + kc];
        }
        __syncthreads();
#pragma unroll
        for (int ks = 0; ks < 64; ks += 32) {
            half8 a0 = *(const half8*)&As[wave*32 + l15][ks + l4*8];
            half8 a1 = *(const half8*)&As[wave*32 + 16 + l15][ks + l4*8];
#pragma unroll
            for (int nb = 0; nb < 4; ++nb) {
                half8 b = *(const half8*)&Bs[nb*16 + l15][ks + l4*8];
                acc[0][nb] = __builtin_amdgcn_mfma_f32_16x16x32_f16(a0, b, acc[0][nb], 0, 0, 0);
                acc[1][nb] = __builtin_amdgcn_mfma_f32_16x16x32_f16(a1, b, acc[1][nb], 0, 0, 0);
            }
        }
        __syncthreads();
    }
#pragma unroll
    for (int m = 0; m < 2; ++m)
#pragma unroll
    for (int nb = 0; nb < 4; ++nb) {
        int col = n0 + nb*16 + l15;
        float bv = bias[col];
#pragma unroll
        for (int r = 0; r < 4; ++r) {
            int grow = row0 + wave*32 + m*16 + l4*4 + r;
            if (grow < M) {
                float v = acc[m][nb][r] + bv;
                if (RELU) v = fmaxf(v, 0.f);
                C[(size_t)grow*ldc + col] = v;
            }
        }
    }
}

// ---------------- pooling + output ----------------
__global__ void k_pool(const float* __restrict__ mo, const int* __restrict__ batch,
                       float* __restrict__ pooled, float* __restrict__ pcnt) {
    int idx = blockIdx.x*256 + threadIdx.x;
    if (idx >= NN*64) return;
    int n = idx >> 6, j = idx & 63;
    int b = batch[n];
    atomicAdd(&pooled[b*64 + j], mo[idx]);
    if (j == 0) atomicAdd(&pcnt[b], 1.0f);
}

__global__ void k_final(const float* __restrict__ pooled, const float* __restrict__ pcnt,
                        const float* __restrict__ outW, const float* __restrict__ outb,
                        float* __restrict__ out) {
    int t = threadIdx.x;
    if (t >= 320) return;
    int b = t / 5, c = t % 5;
    float rc = 1.f / fmaxf(pcnt[b], 1.f);
    float acc = outb[c];
    for (int k = 0; k < 64; ++k) acc += pooled[b*64 + k] * rc * outW[k*5 + c];
    out[t] = acc;
}

extern "C" void kernel_launch(void* const* d_in, const int* in_sizes, int n_in,
                              void* d_out, int out_size, void* d_ws, size_t ws_size,
                              hipStream_t stream) {
    const float* x      = (const float*)d_in[0];
    const int*   ei     = (const int*)d_in[1];
    const float* attr   = (const float*)d_in[2];
    const int*   batch  = (const int*)d_in[3];
    const float* node_W = (const float*)d_in[4];
    const float* node_b = (const float*)d_in[5];
    const float* edge_W = (const float*)d_in[6];
    const float* edge_b = (const float*)d_in[7];
    const float* Wl[2]   = {(const float*)d_in[8],  (const float*)d_in[17]};
    const float* bl[2]   = {(const float*)d_in[9],  (const float*)d_in[18]};
    const float* Wr[2]   = {(const float*)d_in[10], (const float*)d_in[19]};
    const float* br[2]   = {(const float*)d_in[11], (const float*)d_in[20]};
    const float* We[2]   = {(const float*)d_in[12], (const float*)d_in[21]};
    const float* att[2]  = {(const float*)d_in[13], (const float*)d_in[22]};
    const float* bias[2] = {(const float*)d_in[14], (const float*)d_in[23]};
    const float* gamma[2]= {(const float*)d_in[15], (const float*)d_in[24]};
    const float* beta[2] = {(const float*)d_in[16], (const float*)d_in[25]};
    const float* mlp_W = (const float*)d_in[26];
    const float* mlp_b = (const float*)d_in[27];
    const float* out_W = (const float*)d_in[28];
    const float* out_b = (const float*)d_in[29];
    float* out = (float*)d_out;

    char* p = (char*)d_ws;
    size_t off = 0;
    auto carve = [&](size_t bytes) -> void* {
        void* r = p + off;
        off = (off + bytes + 255) & ~(size_t)255;
        return r;
    };
    _Float16* Wpt0   = (_Float16*)carve(256*64*2);
    _Float16* Wpt1   = (_Float16*)carve(256*64*2);
    float*    Acat   = (float*)carve(6*512*4);
    _Float16* WlWr1t = (_Float16*)carve(512*256*2);
    float*    blr1   = (float*)carve(512*4);
    _Float16* mlpWt  = (_Float16*)carve(64*256*2);
    float*    ss     = (float*)carve(512*4);
    float*    xlxr   = (float*)carve((size_t)NN*512*4);
    float*    gat    = (float*)carve((size_t)NN*256*4);
    _Float16* h16    = (_Float16*)carve((size_t)NN*256*2);
    float*    alpha  = (float*)carve((size_t)EE*4*4);
    float*    mlo    = (float*)carve((size_t)NN*64*4);
    int*      row_ptr= (int*)carve((NN+1)*4);
    int*      eid    = (int*)carve((size_t)EE*4);
    int*      csrc   = (int*)carve((size_t)EE*4);
    int*      cursor = (int*)carve(NN*4);
    char*     zz     = (char*)carve((NN + 1024 + 4096 + 64)*4);
    int*      counts = (int*)zz;
    float*    stats  = (float*)(zz + (size_t)NN*4);
    float*    pooled = (float*)(zz + (size_t)(NN+1024)*4);
    float*    pcnt   = (float*)(zz + (size_t)(NN+1024+4096)*4);
    if (off > ws_size) return;  // workspace too small: bail (output stays wrong -> visible signal)

    hipMemsetAsync(zz, 0, (size_t)(NN + 1024 + 4096 + 64)*4, stream);
    k_prep_edgeW<<<dim3(64,2), 256, 0, stream>>>(edge_W, edge_b, We[0], We[1], Wpt0, Wpt1);
    k_prep_acat<<<6, 512, 0, stream>>>(node_W, node_b, Wl[0], bl[0], Wr[0], br[0], Acat);
    k_prep_t16<<<576, 256, 0, stream>>>(Wl[1], bl[1], Wr[1], br[1], mlp_W, WlWr1t, blr1, mlpWt);
    k_hist<<<(EE+255)/256, 256, 0, stream>>>(ei, counts);
    k_scan<<<1, 1024, 0, stream>>>(counts, row_ptr, cursor);
    k_scatter<<<(EE+255)/256, 256, 0, stream>>>(ei, cursor, eid, csrc);
    k_xlxr0<<<NN, 256, 0, stream>>>(x, Acat, xlxr);

    for (int L = 0; L < 2; ++L) {
        k_alpha2<<<1024, 256, 0, stream>>>(attr, ei, L ? Wpt1 : Wpt0, att[L], xlxr, alpha);
        k_agg<<<NN, 256, 0, stream>>>(alpha, eid, csrc, row_ptr, xlxr, bias[L], gat);
        k_bn_stats<<<256, 256, 0, stream>>>(gat, stats + L*512);
        k_bn_final<<<1, 256, 0, stream>>>(stats + L*512, gamma[L], beta[L], ss);
        k_bn_apply<<<NN, 256, 0, stream>>>(gat, ss, h16);
        if (L == 0)
            k_gemm<false><<<dim3(157, 8), 256, 0, stream>>>(h16, WlWr1t, blr1, xlxr, NN, 256, 512);
        else
            k_gemm<true><<<dim3(157, 1), 256, 0, stream>>>(h16, mlpWt, mlp_b, mlo, NN, 256, 64);
    }
    k_pool<<<(NN*64+255)/256, 256, 0, stream>>>(mlo, batch, pooled, pcnt);
    k_final<<<1, 320, 0, stream>>>(pooled, pcnt, out_W, out_b, out);
}

// Round 3
// 711.262 us; speedup vs baseline: 1.6497x; 1.0077x over previous
//
#include <hip/hip_runtime.h>

#define NN 20000
#define EE 320000
#define BB 64

typedef _Float16 half8 __attribute__((ext_vector_type(8)));
typedef float floatx4 __attribute__((ext_vector_type(4)));

// ---------------- prep: weight folding ----------------
// Wpt[layer][j*64+k] = fp16( sum_t edge_W[k][t]*We[t][j] ) for k<63; k=63 row = edge_b@We (bias)
__global__ void k_prep_edgeW(const float* __restrict__ edge_W, const float* __restrict__ edge_b,
                             const float* __restrict__ We0, const float* __restrict__ We1,
                             _Float16* __restrict__ Wpt0, _Float16* __restrict__ Wpt1) {
    __shared__ float row[256];
    int k = blockIdx.x, layer = blockIdx.y, j = threadIdx.x;
    row[j] = (k < 63) ? edge_W[k*256 + j] : edge_b[j];
    __syncthreads();
    const float* We = layer ? We1 : We0;
    float acc = 0.f;
    for (int t = 0; t < 256; ++t) acc += row[t] * We[t*256 + j];
    (layer ? Wpt1 : Wpt0)[j*64 + k] = (_Float16)acc;   // transposed [col][k] fp16
}

// Acat[k][j] (k<5) = sum_d node_W[k][d] * {Wl0|Wr0}[d][j];  row 5 adds node_b path + bl0/br0
__global__ void k_prep_acat(const float* __restrict__ node_W, const float* __restrict__ node_b,
                            const float* __restrict__ Wl0, const float* __restrict__ bl0,
                            const float* __restrict__ Wr0, const float* __restrict__ br0,
                            float* __restrict__ Acat) {
    __shared__ float row[256];
    int k = blockIdx.x, j = threadIdx.x;
    if (j < 256) row[j] = (k < 5) ? node_W[k*256 + j] : node_b[j];
    __syncthreads();
    int jj = j & 255;
    const float* W = (j < 256) ? Wl0 : Wr0;
    float acc = 0.f;
    for (int t = 0; t < 256; ++t) acc += row[t] * W[t*256 + jj];
    if (k == 5) acc += (j < 256) ? bl0[jj] : br0[jj];
    Acat[k*512 + j] = acc;
}

// transpose+fp16: WlWr1t [512][256], blr1[512], mlpWt [64][256]
__global__ void k_prep_t16(const float* __restrict__ Wl1, const float* __restrict__ bl1,
                           const float* __restrict__ Wr1, const float* __restrict__ br1,
                           const float* __restrict__ mlp_W,
                           _Float16* __restrict__ WlWr1t, float* __restrict__ blr1,
                           _Float16* __restrict__ mlpWt) {
    int n = blockIdx.x, k = threadIdx.x;
    if (n < 512) {
        float v = (n < 256) ? Wl1[k*256 + n] : Wr1[k*256 + (n - 256)];
        WlWr1t[n*256 + k] = (_Float16)v;
        if (k == 0) blr1[n] = (n < 256) ? bl1[n] : br1[n - 256];
    } else {
        int nn = n - 512;
        mlpWt[nn*256 + k] = (_Float16)mlp_W[k*64 + nn];
    }
}

// ---------------- CSR by dst ----------------
__global__ void k_hist(const int* __restrict__ ei, int* __restrict__ counts) {
    int e = blockIdx.x*256 + threadIdx.x;
    if (e < EE) atomicAdd(&counts[ei[EE + e]], 1);
}

__global__ __launch_bounds__(1024) void k_scan(const int* __restrict__ counts,
                                               int* __restrict__ row_ptr, int* __restrict__ cursor) {
    __shared__ int part[1024];
    int t = threadIdx.x;
    const int per = (NN + 1023) / 1024;
    int b0 = t*per, b1 = min(b0 + per, NN);
    int s = 0;
    for (int i = b0; i < b1; ++i) s += counts[i];
    part[t] = s; __syncthreads();
    for (int d = 1; d < 1024; d <<= 1) {
        int v = (t >= d) ? part[t-d] : 0;
        __syncthreads();
        part[t] += v;
        __syncthreads();
    }
    int run = (t == 0) ? 0 : part[t-1];
    for (int i = b0; i < b1; ++i) { row_ptr[i] = run; cursor[i] = run; run += counts[i]; }
    if (t == 0) row_ptr[NN] = EE;
}

__global__ void k_scatter(const int* __restrict__ ei, int* __restrict__ cursor,
                          int* __restrict__ eid, int* __restrict__ csr_src,
                          int* __restrict__ dnode) {
    int e = blockIdx.x*256 + threadIdx.x;
    if (e < EE) {
        int d = ei[EE + e];
        int p = atomicAdd(&cursor[d], 1);
        eid[p] = e;
        csr_src[p] = ei[e];
        dnode[p] = d;
    }
}

// permute attr into CSR order, fp32->fp16, 64-wide with bias lane (k=63 -> 1.0)
__global__ void k_permattr(const float* __restrict__ attr, const int* __restrict__ eid,
                           _Float16* __restrict__ attr16) {
    int tid = threadIdx.x;
    int w = tid >> 6, lane = tid & 63;
    int p = blockIdx.x*4 + w;
    if (p >= EE) return;
    int e = eid[p];
    float v = (lane < 63) ? attr[(size_t)e*63 + lane] : 1.0f;
    attr16[(size_t)p*64 + lane] = (_Float16)v;
}

// ---------------- layer 0 xl/xr via folded K=5 (fp16 out) ----------------
__global__ void k_xlxr0(const float* __restrict__ x, const float* __restrict__ Acat,
                        _Float16* __restrict__ xlxr16) {
    int n = blockIdx.x, j = threadIdx.x;
    float a0 = Acat[5*512 + j], a1 = Acat[5*512 + 256 + j];
#pragma unroll
    for (int k = 0; k < 5; ++k) {
        float xv = x[n*5 + k];
        a0 += xv * Acat[k*512 + j];
        a1 += xv * Acat[k*512 + 256 + j];
    }
    xlxr16[(size_t)n*512 + j] = (_Float16)a0;
    xlxr16[(size_t)n*512 + 256 + j] = (_Float16)a1;
}

// ---------------- per-edge alpha, CSR-ordered: MFMA ee + register phase-B ----------------
// wave w = head w. chunk = 64 CSR positions; no LDS, no barriers.
__global__ __launch_bounds__(256) void k_alpha3(const _Float16* __restrict__ attr16,
        const int* __restrict__ csrc, const int* __restrict__ dnode,
        const _Float16* __restrict__ Wpt, const float* __restrict__ att,
        const _Float16* __restrict__ xlxr16, float* __restrict__ alphaP) {
    int tid = threadIdx.x;
    int wave = tid >> 6, lane = tid & 63;
    int l15 = lane & 15, l4 = lane >> 4;

    // chunk-invariant: B-fragments (Wpt[col][k]) + att
    half8 bf[4][2];
    float attv[4];
#pragma unroll
    for (int ct = 0; ct < 4; ++ct) {
        int col = wave*64 + ct*16 + l15;
        attv[ct] = att[col];
#pragma unroll
        for (int ks = 0; ks < 2; ++ks)
            bf[ct][ks] = *(const half8*)&Wpt[(size_t)col*64 + ks*32 + l4*8];
    }

    for (int ch = blockIdx.x; ch < EE/64; ch += gridDim.x) {
        int e0 = ch * 64;
#pragma unroll
        for (int et = 0; et < 4; ++et) {
            int te = e0 + et*16;
            half8 a0 = *(const half8*)&attr16[(size_t)(te + l15)*64 + l4*8];
            half8 a1 = *(const half8*)&attr16[(size_t)(te + l15)*64 + 32 + l4*8];
            floatx4 acc[4];
#pragma unroll
            for (int ct = 0; ct < 4; ++ct) {
                floatx4 z = {};
                acc[ct] = __builtin_amdgcn_mfma_f32_16x16x32_f16(a0, bf[ct][0], z, 0, 0, 0);
                acc[ct] = __builtin_amdgcn_mfma_f32_16x16x32_f16(a1, bf[ct][1], acc[ct], 0, 0, 0);
            }
            int4 sv = *(const int4*)&csrc[te + l4*4];
            int4 dv = *(const int4*)&dnode[te + l4*4];
            int se[4] = {sv.x, sv.y, sv.z, sv.w};
            int de[4] = {dv.x, dv.y, dv.z, dv.w};
#pragma unroll
            for (int r = 0; r < 4; ++r) {
                const _Float16* xp = xlxr16 + (size_t)se[r]*512 + wave*64 + l15;
                const _Float16* rp = xlxr16 + (size_t)de[r]*512 + 256 + wave*64 + l15;
                float p = 0.f;
#pragma unroll
                for (int ct = 0; ct < 4; ++ct) {
                    float m = acc[ct][r] + (float)xp[ct*16] + (float)rp[ct*16];
                    float lr = (m > 0.f) ? m : 0.2f*m;
                    p += lr * attv[ct];
                }
                p += __shfl_xor(p, 1);
                p += __shfl_xor(p, 2);
                p += __shfl_xor(p, 4);
                p += __shfl_xor(p, 8);
                if (l15 == 0) alphaP[(size_t)wave*EE + te + l4*4 + r] = p;
            }
        }
    }
}

// ---------------- per-dst softmax + aggregate (fp16 gather) ----------------
__global__ __launch_bounds__(256) void k_agg(const float* __restrict__ alphaP,
                      const int* __restrict__ csr_src, const int* __restrict__ row_ptr,
                      const _Float16* __restrict__ xlxr16, const float* __restrict__ bias,
                      float* __restrict__ gat) {
    int n = blockIdx.x, j = threadIdx.x;
    int h = j >> 6, lane = j & 63;
    int s = row_ptr[n], e = row_ptr[n+1];
    if (e <= s) { gat[(size_t)n*256 + j] = bias[j]; return; }
    const float* ap = alphaP + (size_t)h*EE;
    float mx = -3.0e38f;
    for (int p = s + lane; p < e; p += 64) mx = fmaxf(mx, ap[p]);
#pragma unroll
    for (int m = 1; m < 64; m <<= 1) mx = fmaxf(mx, __shfl_xor(mx, m));
    float sm = 0.f;
    for (int p = s + lane; p < e; p += 64) sm += __expf(ap[p] - mx);
#pragma unroll
    for (int m = 1; m < 64; m <<= 1) sm += __shfl_xor(sm, m);
    float rden = 1.0f / sm;
    float acc = 0.f;
    for (int p = s; p < e; ++p) {
        float wgt = __expf(ap[p] - mx) * rden;
        acc += wgt * (float)xlxr16[(size_t)csr_src[p]*512 + j];
    }
    gat[(size_t)n*256 + j] = acc + bias[j];
}

// ---------------- batchnorm ----------------
__global__ void k_bn_stats(const float* __restrict__ X, float* __restrict__ stats) {
    int j = threadIdx.x;
    float s = 0.f, q = 0.f;
    for (int r = blockIdx.x; r < NN; r += gridDim.x) {
        float v = X[(size_t)r*256 + j];
        s += v; q += v*v;
    }
    atomicAdd(&stats[j], s);
    atomicAdd(&stats[256 + j], q);
}

__global__ void k_bn_final(const float* __restrict__ stats, const float* __restrict__ gamma,
                           const float* __restrict__ beta, float* __restrict__ ss) {
    int j = threadIdx.x;
    float mean = stats[j] * (1.0f/NN);
    float var  = stats[256 + j] * (1.0f/NN) - mean*mean;
    float sc = rsqrtf(var + 1e-5f) * gamma[j];
    ss[j] = sc;
    ss[256 + j] = beta[j] - mean*sc;
}

__global__ void k_bn_apply(const float* __restrict__ X, const float* __restrict__ ss,
                           _Float16* __restrict__ Hh) {
    size_t idx = (size_t)blockIdx.x*256 + threadIdx.x;
    int col = threadIdx.x;  // rows are 256 wide, blockDim=256
    float v = X[idx]*ss[col] + ss[256+col];
    Hh[idx] = (_Float16)fmaxf(v, 0.f);
}

// ---------------- fp16 MFMA GEMM: C[M,cols] = A[M,K] @ Bt[N,K]^T + bias ----------------
template<bool RELU, typename OT>
__global__ __launch_bounds__(256) void k_gemm(const _Float16* __restrict__ A, const _Float16* __restrict__ Bt,
                       const float* __restrict__ bias, OT* __restrict__ C,
                       int M, int K, int ldc) {
    __shared__ __align__(16) _Float16 As[128][72];
    __shared__ __align__(16) _Float16 Bs[64][72];
    int tid = threadIdx.x;
    int wave = tid >> 6, lane = tid & 63;
    int l15 = lane & 15, l4 = lane >> 4;
    int row0 = blockIdx.x*128, n0 = blockIdx.y*64;
    floatx4 acc[2][4] = {};
    for (int k0 = 0; k0 < K; k0 += 64) {
#pragma unroll
        for (int q = 0; q < 4; ++q) {
            int c = tid + q*256;
            int r = c >> 3, kc = (c & 7)*8;
            int gr = row0 + r; if (gr >= M) gr = M - 1;
            *(half8*)&As[r][kc] = *(const half8*)&A[(size_t)gr*K + k0 + kc];
        }
#pragma unroll
        for (int q = 0; q < 2; ++q) {
            int c = tid + q*256;
            int r = c >> 3, kc = (c & 7)*8;
            *(half8*)&Bs[r][kc] = *(const half8*)&Bt[(size_t)(n0 + r)*K + k0 + kc];
        }
        __syncthreads();
#pragma unroll
        for (int ks = 0; ks < 64; ks += 32) {
            half8 a0 = *(const half8*)&As[wave*32 + l15][ks + l4*8];
            half8 a1 = *(const half8*)&As[wave*32 + 16 + l15][ks + l4*8];
#pragma unroll
            for (int nb = 0; nb < 4; ++nb) {
                half8 b = *(const half8*)&Bs[nb*16 + l15][ks + l4*8];
                acc[0][nb] = __builtin_amdgcn_mfma_f32_16x16x32_f16(a0, b, acc[0][nb], 0, 0, 0);
                acc[1][nb] = __builtin_amdgcn_mfma_f32_16x16x32_f16(a1, b, acc[1][nb], 0, 0, 0);
            }
        }
        __syncthreads();
    }
#pragma unroll
    for (int m = 0; m < 2; ++m)
#pragma unroll
    for (int nb = 0; nb < 4; ++nb) {
        int col = n0 + nb*16 + l15;
        float bv = bias[col];
#pragma unroll
        for (int r = 0; r < 4; ++r) {
            int grow = row0 + wave*32 + m*16 + l4*4 + r;
            if (grow < M) {
                float v = acc[m][nb][r] + bv;
                if (RELU) v = fmaxf(v, 0.f);
                C[(size_t)grow*ldc + col] = (OT)v;
            }
        }
    }
}

// ---------------- pooling + output ----------------
__global__ void k_pool(const float* __restrict__ mo, const int* __restrict__ batch,
                       float* __restrict__ pooled, float* __restrict__ pcnt) {
    int idx = blockIdx.x*256 + threadIdx.x;
    if (idx >= NN*64) return;
    int n = idx >> 6, j = idx & 63;
    int b = batch[n];
    atomicAdd(&pooled[b*64 + j], mo[idx]);
    if (j == 0) atomicAdd(&pcnt[b], 1.0f);
}

__global__ void k_final(const float* __restrict__ pooled, const float* __restrict__ pcnt,
                        const float* __restrict__ outW, const float* __restrict__ outb,
                        float* __restrict__ out) {
    int t = threadIdx.x;
    if (t >= 320) return;
    int b = t / 5, c = t % 5;
    float rc = 1.f / fmaxf(pcnt[b], 1.f);
    float acc = outb[c];
    for (int k = 0; k < 64; ++k) acc += pooled[b*64 + k] * rc * outW[k*5 + c];
    out[t] = acc;
}

extern "C" void kernel_launch(void* const* d_in, const int* in_sizes, int n_in,
                              void* d_out, int out_size, void* d_ws, size_t ws_size,
                              hipStream_t stream) {
    const float* x      = (const float*)d_in[0];
    const int*   ei     = (const int*)d_in[1];
    const float* attr   = (const float*)d_in[2];
    const int*   batch  = (const int*)d_in[3];
    const float* node_W = (const float*)d_in[4];
    const float* node_b = (const float*)d_in[5];
    const float* edge_W = (const float*)d_in[6];
    const float* edge_b = (const float*)d_in[7];
    const float* Wl[2]   = {(const float*)d_in[8],  (const float*)d_in[17]};
    const float* bl[2]   = {(const float*)d_in[9],  (const float*)d_in[18]};
    const float* Wr[2]   = {(const float*)d_in[10], (const float*)d_in[19]};
    const float* br[2]   = {(const float*)d_in[11], (const float*)d_in[20]};
    const float* We[2]   = {(const float*)d_in[12], (const float*)d_in[21]};
    const float* att[2]  = {(const float*)d_in[13], (const float*)d_in[22]};
    const float* bias[2] = {(const float*)d_in[14], (const float*)d_in[23]};
    const float* gamma[2]= {(const float*)d_in[15], (const float*)d_in[24]};
    const float* beta[2] = {(const float*)d_in[16], (const float*)d_in[25]};
    const float* mlp_W = (const float*)d_in[26];
    const float* mlp_b = (const float*)d_in[27];
    const float* out_W = (const float*)d_in[28];
    const float* out_b = (const float*)d_in[29];
    float* out = (float*)d_out;

    char* p = (char*)d_ws;
    size_t off = 0;
    auto carve = [&](size_t bytes) -> void* {
        void* r = p + off;
        off = (off + bytes + 255) & ~(size_t)255;
        return r;
    };
    _Float16* Wpt0   = (_Float16*)carve(256*64*2);
    _Float16* Wpt1   = (_Float16*)carve(256*64*2);
    float*    Acat   = (float*)carve(6*512*4);
    _Float16* WlWr1t = (_Float16*)carve(512*256*2);
    float*    blr1   = (float*)carve(512*4);
    _Float16* mlpWt  = (_Float16*)carve(64*256*2);
    float*    ss     = (float*)carve(512*4);
    _Float16* xlxr16 = (_Float16*)carve((size_t)NN*512*2);
    float*    gat    = (float*)carve((size_t)NN*256*4);
    _Float16* h16    = (_Float16*)carve((size_t)NN*256*2);
    float*    alphaP = (float*)carve((size_t)EE*4*4);
    float*    mlo    = (float*)carve((size_t)NN*64*4);
    _Float16* attr16 = (_Float16*)carve((size_t)EE*64*2);
    int*      dnode  = (int*)carve((size_t)EE*4);
    int*      row_ptr= (int*)carve((NN+1)*4);
    int*      eid    = (int*)carve((size_t)EE*4);
    int*      csrc   = (int*)carve((size_t)EE*4);
    int*      cursor = (int*)carve(NN*4);
    char*     zz     = (char*)carve((NN + 1024 + 4096 + 64)*4);
    int*      counts = (int*)zz;
    float*    stats  = (float*)(zz + (size_t)NN*4);
    float*    pooled = (float*)(zz + (size_t)(NN+1024)*4);
    float*    pcnt   = (float*)(zz + (size_t)(NN+1024+4096)*4);
    if (off > ws_size) return;  // workspace too small: bail (output stays wrong -> visible signal)

    hipMemsetAsync(zz, 0, (size_t)(NN + 1024 + 4096 + 64)*4, stream);
    k_prep_edgeW<<<dim3(64,2), 256, 0, stream>>>(edge_W, edge_b, We[0], We[1], Wpt0, Wpt1);
    k_prep_acat<<<6, 512, 0, stream>>>(node_W, node_b, Wl[0], bl[0], Wr[0], br[0], Acat);
    k_prep_t16<<<576, 256, 0, stream>>>(Wl[1], bl[1], Wr[1], br[1], mlp_W, WlWr1t, blr1, mlpWt);
    k_hist<<<(EE+255)/256, 256, 0, stream>>>(ei, counts);
    k_scan<<<1, 1024, 0, stream>>>(counts, row_ptr, cursor);
    k_scatter<<<(EE+255)/256, 256, 0, stream>>>(ei, cursor, eid, csrc, dnode);
    k_permattr<<<EE/4, 256, 0, stream>>>(attr, eid, attr16);
    k_xlxr0<<<NN, 256, 0, stream>>>(x, Acat, xlxr16);

    for (int L = 0; L < 2; ++L) {
        k_alpha3<<<1250, 256, 0, stream>>>(attr16, csrc, dnode, L ? Wpt1 : Wpt0, att[L], xlxr16, alphaP);
        k_agg<<<NN, 256, 0, stream>>>(alphaP, csrc, row_ptr, xlxr16, bias[L], gat);
        k_bn_stats<<<256, 256, 0, stream>>>(gat, stats + L*512);
        k_bn_final<<<1, 256, 0, stream>>>(stats + L*512, gamma[L], beta[L], ss);
        k_bn_apply<<<NN, 256, 0, stream>>>(gat, ss, h16);
        if (L == 0)
            k_gemm<false, _Float16><<<dim3(157, 8), 256, 0, stream>>>(h16, WlWr1t, blr1, xlxr16, NN, 256, 512);
        else
            k_gemm<true, float><<<dim3(157, 1), 256, 0, stream>>>(h16, mlpWt, mlp_b, mlo, NN, 256, 64);
    }
    k_pool<<<(NN*64+255)/256, 256, 0, stream>>>(mlo, batch, pooled, pcnt);
    k_final<<<1, 320, 0, stream>>>(pooled, pcnt, out_W, out_b, out);
}

// Round 4
// 616.444 us; speedup vs baseline: 1.9035x; 1.1538x over previous
//
#include <hip/hip_runtime.h>

#define NN 20000
#define EE 320000
#define BB 64

typedef _Float16 half8 __attribute__((ext_vector_type(8)));
typedef float floatx4 __attribute__((ext_vector_type(4)));

// ---------------- prep: weight folding ----------------
// Wpt[layer][j*64+k] = fp16( sum_t edge_W[k][t]*We[t][j] ) for k<63; k=63 row = edge_b@We (bias)
__global__ void k_prep_edgeW(const float* __restrict__ edge_W, const float* __restrict__ edge_b,
                             const float* __restrict__ We0, const float* __restrict__ We1,
                             _Float16* __restrict__ Wpt0, _Float16* __restrict__ Wpt1) {
    __shared__ float row[256];
    int k = blockIdx.x, layer = blockIdx.y, j = threadIdx.x;
    row[j] = (k < 63) ? edge_W[k*256 + j] : edge_b[j];
    __syncthreads();
    const float* We = layer ? We1 : We0;
    float acc = 0.f;
    for (int t = 0; t < 256; ++t) acc += row[t] * We[t*256 + j];
    (layer ? Wpt1 : Wpt0)[j*64 + k] = (_Float16)acc;   // transposed [col][k] fp16
}

// Acat[k][j] (k<5) = sum_d node_W[k][d] * {Wl0|Wr0}[d][j];  row 5 adds node_b path + bl0/br0
__global__ void k_prep_acat(const float* __restrict__ node_W, const float* __restrict__ node_b,
                            const float* __restrict__ Wl0, const float* __restrict__ bl0,
                            const float* __restrict__ Wr0, const float* __restrict__ br0,
                            float* __restrict__ Acat) {
    __shared__ float row[256];
    int k = blockIdx.x, j = threadIdx.x;
    if (j < 256) row[j] = (k < 5) ? node_W[k*256 + j] : node_b[j];
    __syncthreads();
    int jj = j & 255;
    const float* W = (j < 256) ? Wl0 : Wr0;
    float acc = 0.f;
    for (int t = 0; t < 256; ++t) acc += row[t] * W[t*256 + jj];
    if (k == 5) acc += (j < 256) ? bl0[jj] : br0[jj];
    Acat[k*512 + j] = acc;
}

// transpose+fp16: WlWr1t [512][256], blr1[512], mlpWt [64][256]
__global__ void k_prep_t16(const float* __restrict__ Wl1, const float* __restrict__ bl1,
                           const float* __restrict__ Wr1, const float* __restrict__ br1,
                           const float* __restrict__ mlp_W,
                           _Float16* __restrict__ WlWr1t, float* __restrict__ blr1,
                           _Float16* __restrict__ mlpWt) {
    int n = blockIdx.x, k = threadIdx.x;
    if (n < 512) {
        float v = (n < 256) ? Wl1[k*256 + n] : Wr1[k*256 + (n - 256)];
        WlWr1t[n*256 + k] = (_Float16)v;
        if (k == 0) blr1[n] = (n < 256) ? bl1[n] : br1[n - 256];
    } else {
        int nn = n - 512;
        mlpWt[nn*256 + k] = (_Float16)mlp_W[k*64 + nn];
    }
}

// ---------------- CSR by dst ----------------
__global__ void k_hist(const int* __restrict__ ei, int* __restrict__ counts) {
    int e = blockIdx.x*256 + threadIdx.x;
    if (e < EE) atomicAdd(&counts[ei[EE + e]], 1);
}

__global__ __launch_bounds__(1024) void k_scan(const int* __restrict__ counts,
                                               int* __restrict__ row_ptr, int* __restrict__ cursor) {
    __shared__ int part[1024];
    int t = threadIdx.x;
    const int per = (NN + 1023) / 1024;
    int b0 = t*per, b1 = min(b0 + per, NN);
    int s = 0;
    for (int i = b0; i < b1; ++i) s += counts[i];
    part[t] = s; __syncthreads();
    for (int d = 1; d < 1024; d <<= 1) {
        int v = (t >= d) ? part[t-d] : 0;
        __syncthreads();
        part[t] += v;
        __syncthreads();
    }
    int run = (t == 0) ? 0 : part[t-1];
    for (int i = b0; i < b1; ++i) { row_ptr[i] = run; cursor[i] = run; run += counts[i]; }
    if (t == 0) row_ptr[NN] = EE;
}

__global__ void k_scatter(const int* __restrict__ ei, int* __restrict__ cursor,
                          int* __restrict__ pos, int* __restrict__ csr_src,
                          int* __restrict__ dnode) {
    int e = blockIdx.x*256 + threadIdx.x;
    if (e < EE) {
        int d = ei[EE + e];
        int p = atomicAdd(&cursor[d], 1);
        pos[e] = p;
        csr_src[p] = ei[e];
        dnode[p] = d;
    }
}

// permute attr into CSR order (coalesced read, scattered 128B write), fp32->fp16,
// 64-wide with bias lane (k=63 -> 1.0)
__global__ void k_permattr(const float* __restrict__ attr, const int* __restrict__ pos,
                           _Float16* __restrict__ attr16) {
    int tid = threadIdx.x;
    int w = tid >> 6, lane = tid & 63;
    int e = blockIdx.x*4 + w;
    if (e >= EE) return;
    float v = (lane < 63) ? attr[(size_t)e*63 + lane] : 1.0f;
    attr16[(size_t)pos[e]*64 + lane] = (_Float16)v;
}

// ---------------- layer 0 xl/xr via folded K=5 (fp16 out) ----------------
__global__ void k_xlxr0(const float* __restrict__ x, const float* __restrict__ Acat,
                        _Float16* __restrict__ xlxr16) {
    int n = blockIdx.x, j = threadIdx.x;
    float a0 = Acat[5*512 + j], a1 = Acat[5*512 + 256 + j];
#pragma unroll
    for (int k = 0; k < 5; ++k) {
        float xv = x[n*5 + k];
        a0 += xv * Acat[k*512 + j];
        a1 += xv * Acat[k*512 + 256 + j];
    }
    xlxr16[(size_t)n*512 + j] = (_Float16)a0;
    xlxr16[(size_t)n*512 + 256 + j] = (_Float16)a1;
}

// ---------------- per-edge alpha, CSR-ordered: MFMA ee + register phase-B ----------------
// wave w = head w. chunk = 64 CSR positions; no LDS, no barriers.
__global__ __launch_bounds__(256) void k_alpha3(const _Float16* __restrict__ attr16,
        const int* __restrict__ csrc, const int* __restrict__ dnode,
        const _Float16* __restrict__ Wpt, const float* __restrict__ att,
        const _Float16* __restrict__ xlxr16, float* __restrict__ alphaP) {
    int tid = threadIdx.x;
    int wave = tid >> 6, lane = tid & 63;
    int l15 = lane & 15, l4 = lane >> 4;

    // chunk-invariant: B-fragments (Wpt[col][k]) + att
    half8 bf[4][2];
    float attv[4];
#pragma unroll
    for (int ct = 0; ct < 4; ++ct) {
        int col = wave*64 + ct*16 + l15;
        attv[ct] = att[col];
#pragma unroll
        for (int ks = 0; ks < 2; ++ks)
            bf[ct][ks] = *(const half8*)&Wpt[(size_t)col*64 + ks*32 + l4*8];
    }

    for (int ch = blockIdx.x; ch < EE/64; ch += gridDim.x) {
        int e0 = ch * 64;
#pragma unroll
        for (int et = 0; et < 4; ++et) {
            int te = e0 + et*16;
            half8 a0 = *(const half8*)&attr16[(size_t)(te + l15)*64 + l4*8];
            half8 a1 = *(const half8*)&attr16[(size_t)(te + l15)*64 + 32 + l4*8];
            floatx4 acc[4];
#pragma unroll
            for (int ct = 0; ct < 4; ++ct) {
                floatx4 z = {};
                acc[ct] = __builtin_amdgcn_mfma_f32_16x16x32_f16(a0, bf[ct][0], z, 0, 0, 0);
                acc[ct] = __builtin_amdgcn_mfma_f32_16x16x32_f16(a1, bf[ct][1], acc[ct], 0, 0, 0);
            }
            int4 sv = *(const int4*)&csrc[te + l4*4];
            int4 dv = *(const int4*)&dnode[te + l4*4];
            int se[4] = {sv.x, sv.y, sv.z, sv.w};
            int de[4] = {dv.x, dv.y, dv.z, dv.w};
#pragma unroll
            for (int r = 0; r < 4; ++r) {
                const _Float16* xp = xlxr16 + (size_t)se[r]*512 + wave*64 + l15;
                const _Float16* rp = xlxr16 + (size_t)de[r]*512 + 256 + wave*64 + l15;
                float p = 0.f;
#pragma unroll
                for (int ct = 0; ct < 4; ++ct) {
                    float m = acc[ct][r] + (float)xp[ct*16] + (float)rp[ct*16];
                    float lr = (m > 0.f) ? m : 0.2f*m;
                    p += lr * attv[ct];
                }
                p += __shfl_xor(p, 1);
                p += __shfl_xor(p, 2);
                p += __shfl_xor(p, 4);
                p += __shfl_xor(p, 8);
                if (l15 == 0) alphaP[(size_t)wave*EE + te + l4*4 + r] = p;
            }
        }
    }
}

// ---------------- per-dst softmax + aggregate (fp16 gather) ----------------
__global__ __launch_bounds__(256) void k_agg(const float* __restrict__ alphaP,
                      const int* __restrict__ csr_src, const int* __restrict__ row_ptr,
                      const _Float16* __restrict__ xlxr16, const float* __restrict__ bias,
                      float* __restrict__ gat) {
    int n = blockIdx.x, j = threadIdx.x;
    int h = j >> 6, lane = j & 63;
    int s = row_ptr[n], e = row_ptr[n+1];
    if (e <= s) { gat[(size_t)n*256 + j] = bias[j]; return; }
    const float* ap = alphaP + (size_t)h*EE;
    float mx = -3.0e38f;
    for (int p = s + lane; p < e; p += 64) mx = fmaxf(mx, ap[p]);
#pragma unroll
    for (int m = 1; m < 64; m <<= 1) mx = fmaxf(mx, __shfl_xor(mx, m));
    float sm = 0.f;
    for (int p = s + lane; p < e; p += 64) sm += __expf(ap[p] - mx);
#pragma unroll
    for (int m = 1; m < 64; m <<= 1) sm += __shfl_xor(sm, m);
    float rden = 1.0f / sm;
    float acc = 0.f;
    for (int p = s; p < e; ++p) {
        float wgt = __expf(ap[p] - mx) * rden;
        acc += wgt * (float)xlxr16[(size_t)csr_src[p]*512 + j];
    }
    gat[(size_t)n*256 + j] = acc + bias[j];
}

// ---------------- batchnorm ----------------
__global__ void k_bn_stats(const float* __restrict__ X, float* __restrict__ stats) {
    int j = threadIdx.x;
    float s = 0.f, q = 0.f;
    for (int r = blockIdx.x; r < NN; r += gridDim.x) {
        float v = X[(size_t)r*256 + j];
        s += v; q += v*v;
    }
    atomicAdd(&stats[j], s);
    atomicAdd(&stats[256 + j], q);
}

__global__ void k_bn_final(const float* __restrict__ stats, const float* __restrict__ gamma,
                           const float* __restrict__ beta, float* __restrict__ ss) {
    int j = threadIdx.x;
    float mean = stats[j] * (1.0f/NN);
    float var  = stats[256 + j] * (1.0f/NN) - mean*mean;
    float sc = rsqrtf(var + 1e-5f) * gamma[j];
    ss[j] = sc;
    ss[256 + j] = beta[j] - mean*sc;
}

__global__ void k_bn_apply(const float* __restrict__ X, const float* __restrict__ ss,
                           _Float16* __restrict__ Hh) {
    size_t idx = (size_t)blockIdx.x*256 + threadIdx.x;
    int col = threadIdx.x;  // rows are 256 wide, blockDim=256
    float v = X[idx]*ss[col] + ss[256+col];
    Hh[idx] = (_Float16)fmaxf(v, 0.f);
}

// ---------------- fp16 MFMA GEMM: C[M,cols] = A[M,K] @ Bt[N,K]^T + bias ----------------
template<bool RELU, typename OT>
__global__ __launch_bounds__(256) void k_gemm(const _Float16* __restrict__ A, const _Float16* __restrict__ Bt,
                       const float* __restrict__ bias, OT* __restrict__ C,
                       int M, int K, int ldc) {
    __shared__ __align__(16) _Float16 As[128][72];
    __shared__ __align__(16) _Float16 Bs[64][72];
    int tid = threadIdx.x;
    int wave = tid >> 6, lane = tid & 63;
    int l15 = lane & 15, l4 = lane >> 4;
    int row0 = blockIdx.x*128, n0 = blockIdx.y*64;
    floatx4 acc[2][4] = {};
    for (int k0 = 0; k0 < K; k0 += 64) {
#pragma unroll
        for (int q = 0; q < 4; ++q) {
            int c = tid + q*256;
            int r = c >> 3, kc = (c & 7)*8;
            int gr = row0 + r; if (gr >= M) gr = M - 1;
            *(half8*)&As[r][kc] = *(const half8*)&A[(size_t)gr*K + k0 + kc];
        }
#pragma unroll
        for (int q = 0; q < 2; ++q) {
            int c = tid + q*256;
            int r = c >> 3, kc = (c & 7)*8;
            *(half8*)&Bs[r][kc] = *(const half8*)&Bt[(size_t)(n0 + r)*K + k0 + kc];
        }
        __syncthreads();
#pragma unroll
        for (int ks = 0; ks < 64; ks += 32) {
            half8 a0 = *(const half8*)&As[wave*32 + l15][ks + l4*8];
            half8 a1 = *(const half8*)&As[wave*32 + 16 + l15][ks + l4*8];
#pragma unroll
            for (int nb = 0; nb < 4; ++nb) {
                half8 b = *(const half8*)&Bs[nb*16 + l15][ks + l4*8];
                acc[0][nb] = __builtin_amdgcn_mfma_f32_16x16x32_f16(a0, b, acc[0][nb], 0, 0, 0);
                acc[1][nb] = __builtin_amdgcn_mfma_f32_16x16x32_f16(a1, b, acc[1][nb], 0, 0, 0);
            }
        }
        __syncthreads();
    }
#pragma unroll
    for (int m = 0; m < 2; ++m)
#pragma unroll
    for (int nb = 0; nb < 4; ++nb) {
        int col = n0 + nb*16 + l15;
        float bv = bias[col];
#pragma unroll
        for (int r = 0; r < 4; ++r) {
            int grow = row0 + wave*32 + m*16 + l4*4 + r;
            if (grow < M) {
                float v = acc[m][nb][r] + bv;
                if (RELU) v = fmaxf(v, 0.f);
                C[(size_t)grow*ldc + col] = (OT)v;
            }
        }
    }
}

// ---------------- pooling (batch sorted -> contiguous ranges, no atomics) ----------------
__global__ void k_pool2(const float* __restrict__ mo, const int* __restrict__ batch,
                        float* __restrict__ pooledDiv) {
    int b = blockIdx.x;
    int j = threadIdx.x & 63, rg = threadIdx.x >> 6;
    int lo = 0, hi = NN;
    while (lo < hi) { int mid = (lo + hi) >> 1; if (batch[mid] < b) lo = mid + 1; else hi = mid; }
    int s = lo;
    lo = 0; hi = NN;
    while (lo < hi) { int mid = (lo + hi) >> 1; if (batch[mid] < b + 1) lo = mid + 1; else hi = mid; }
    int e = lo;
    float acc = 0.f;
    for (int r = s + rg; r < e; r += 4) acc += mo[(size_t)r*64 + j];
    __shared__ float red[256];
    red[threadIdx.x] = acc;
    __syncthreads();
    if (rg == 0) {
        float v = red[j] + red[64 + j] + red[128 + j] + red[192 + j];
        pooledDiv[b*64 + j] = v / fmaxf((float)(e - s), 1.f);
    }
}

__global__ void k_final(const float* __restrict__ pooledDiv,
                        const float* __restrict__ outW, const float* __restrict__ outb,
                        float* __restrict__ out) {
    int t = threadIdx.x;
    if (t >= 320) return;
    int b = t / 5, c = t % 5;
    float acc = outb[c];
    for (int k = 0; k < 64; ++k) acc += pooledDiv[b*64 + k] * outW[k*5 + c];
    out[t] = acc;
}

extern "C" void kernel_launch(void* const* d_in, const int* in_sizes, int n_in,
                              void* d_out, int out_size, void* d_ws, size_t ws_size,
                              hipStream_t stream) {
    const float* x      = (const float*)d_in[0];
    const int*   ei     = (const int*)d_in[1];
    const float* attr   = (const float*)d_in[2];
    const int*   batch  = (const int*)d_in[3];
    const float* node_W = (const float*)d_in[4];
    const float* node_b = (const float*)d_in[5];
    const float* edge_W = (const float*)d_in[6];
    const float* edge_b = (const float*)d_in[7];
    const float* Wl[2]   = {(const float*)d_in[8],  (const float*)d_in[17]};
    const float* bl[2]   = {(const float*)d_in[9],  (const float*)d_in[18]};
    const float* Wr[2]   = {(const float*)d_in[10], (const float*)d_in[19]};
    const float* br[2]   = {(const float*)d_in[11], (const float*)d_in[20]};
    const float* We[2]   = {(const float*)d_in[12], (const float*)d_in[21]};
    const float* att[2]  = {(const float*)d_in[13], (const float*)d_in[22]};
    const float* bias[2] = {(const float*)d_in[14], (const float*)d_in[23]};
    const float* gamma[2]= {(const float*)d_in[15], (const float*)d_in[24]};
    const float* beta[2] = {(const float*)d_in[16], (const float*)d_in[25]};
    const float* mlp_W = (const float*)d_in[26];
    const float* mlp_b = (const float*)d_in[27];
    const float* out_W = (const float*)d_in[28];
    const float* out_b = (const float*)d_in[29];
    float* out = (float*)d_out;

    char* p = (char*)d_ws;
    size_t off = 0;
    auto carve = [&](size_t bytes) -> void* {
        void* r = p + off;
        off = (off + bytes + 255) & ~(size_t)255;
        return r;
    };
    _Float16* Wpt0   = (_Float16*)carve(256*64*2);
    _Float16* Wpt1   = (_Float16*)carve(256*64*2);
    float*    Acat   = (float*)carve(6*512*4);
    _Float16* WlWr1t = (_Float16*)carve(512*256*2);
    float*    blr1   = (float*)carve(512*4);
    _Float16* mlpWt  = (_Float16*)carve(64*256*2);
    float*    ss     = (float*)carve(512*4);
    _Float16* xlxr16 = (_Float16*)carve((size_t)NN*512*2);
    float*    gat    = (float*)carve((size_t)NN*256*4);
    _Float16* h16    = (_Float16*)carve((size_t)NN*256*2);
    float*    alphaP = (float*)carve((size_t)EE*4*4);
    float*    mlo    = (float*)carve((size_t)NN*64*4);
    _Float16* attr16 = (_Float16*)carve((size_t)EE*64*2);
    int*      dnode  = (int*)carve((size_t)EE*4);
    int*      row_ptr= (int*)carve((NN+1)*4);
    int*      pos    = (int*)carve((size_t)EE*4);
    int*      csrc   = (int*)carve((size_t)EE*4);
    int*      cursor = (int*)carve(NN*4);
    float*    pooledDiv = (float*)carve(BB*64*4);
    char*     zz     = (char*)carve((NN + 1024)*4);
    int*      counts = (int*)zz;
    float*    stats  = (float*)(zz + (size_t)NN*4);
    if (off > ws_size) return;  // workspace too small: bail (output stays wrong -> visible signal)

    hipMemsetAsync(zz, 0, (size_t)(NN + 1024)*4, stream);
    k_prep_edgeW<<<dim3(64,2), 256, 0, stream>>>(edge_W, edge_b, We[0], We[1], Wpt0, Wpt1);
    k_prep_acat<<<6, 512, 0, stream>>>(node_W, node_b, Wl[0], bl[0], Wr[0], br[0], Acat);
    k_prep_t16<<<576, 256, 0, stream>>>(Wl[1], bl[1], Wr[1], br[1], mlp_W, WlWr1t, blr1, mlpWt);
    k_hist<<<(EE+255)/256, 256, 0, stream>>>(ei, counts);
    k_scan<<<1, 1024, 0, stream>>>(counts, row_ptr, cursor);
    k_scatter<<<(EE+255)/256, 256, 0, stream>>>(ei, cursor, pos, csrc, dnode);
    k_permattr<<<EE/4, 256, 0, stream>>>(attr, pos, attr16);
    k_xlxr0<<<NN, 256, 0, stream>>>(x, Acat, xlxr16);

    for (int L = 0; L < 2; ++L) {
        k_alpha3<<<1250, 256, 0, stream>>>(attr16, csrc, dnode, L ? Wpt1 : Wpt0, att[L], xlxr16, alphaP);
        k_agg<<<NN, 256, 0, stream>>>(alphaP, csrc, row_ptr, xlxr16, bias[L], gat);
        k_bn_stats<<<256, 256, 0, stream>>>(gat, stats + L*512);
        k_bn_final<<<1, 256, 0, stream>>>(stats + L*512, gamma[L], beta[L], ss);
        k_bn_apply<<<NN, 256, 0, stream>>>(gat, ss, h16);
        if (L == 0)
            k_gemm<false, _Float16><<<dim3(157, 8), 256, 0, stream>>>(h16, WlWr1t, blr1, xlxr16, NN, 256, 512);
        else
            k_gemm<true, float><<<dim3(157, 1), 256, 0, stream>>>(h16, mlpWt, mlp_b, mlo, NN, 256, 64);
    }
    k_pool2<<<BB, 256, 0, stream>>>(mlo, batch, pooledDiv);
    k_final<<<1, 320, 0, stream>>>(pooledDiv, out_W, out_b, out);
}

// Round 5
// 535.833 us; speedup vs baseline: 2.1898x; 1.1504x over previous
//
#include <hip/hip_runtime.h>

#define NN 20000
#define EE 320000
#define BB 64

typedef _Float16 half8 __attribute__((ext_vector_type(8)));
typedef _Float16 half4 __attribute__((ext_vector_type(4)));
typedef float floatx4 __attribute__((ext_vector_type(4)));

// ---------------- prep: weight folding ----------------
// Wpt[layer][j*64+k] = fp16( sum_t edge_W[k][t]*We[t][j] ) for k<63; k=63 row = edge_b@We (bias)
__global__ void k_prep_edgeW(const float* __restrict__ edge_W, const float* __restrict__ edge_b,
                             const float* __restrict__ We0, const float* __restrict__ We1,
                             _Float16* __restrict__ Wpt0, _Float16* __restrict__ Wpt1) {
    __shared__ float row[256];
    int k = blockIdx.x, layer = blockIdx.y, j = threadIdx.x;
    row[j] = (k < 63) ? edge_W[k*256 + j] : edge_b[j];
    __syncthreads();
    const float* We = layer ? We1 : We0;
    float acc = 0.f;
    for (int t = 0; t < 256; ++t) acc += row[t] * We[t*256 + j];
    (layer ? Wpt1 : Wpt0)[j*64 + k] = (_Float16)acc;   // transposed [col][k] fp16
}

// Acat[k][j] (k<5) = sum_d node_W[k][d] * {Wl0|Wr0}[d][j];  row 5 adds node_b path + bl0/br0
__global__ void k_prep_acat(const float* __restrict__ node_W, const float* __restrict__ node_b,
                            const float* __restrict__ Wl0, const float* __restrict__ bl0,
                            const float* __restrict__ Wr0, const float* __restrict__ br0,
                            float* __restrict__ Acat) {
    __shared__ float row[256];
    int k = blockIdx.x, j = threadIdx.x;
    if (j < 256) row[j] = (k < 5) ? node_W[k*256 + j] : node_b[j];
    __syncthreads();
    int jj = j & 255;
    const float* W = (j < 256) ? Wl0 : Wr0;
    float acc = 0.f;
    for (int t = 0; t < 256; ++t) acc += row[t] * W[t*256 + jj];
    if (k == 5) acc += (j < 256) ? bl0[jj] : br0[jj];
    Acat[k*512 + j] = acc;
}

// transpose+fp16: WlWr1t [512][256], blr1[512], mlpWt [64][256]
__global__ void k_prep_t16(const float* __restrict__ Wl1, const float* __restrict__ bl1,
                           const float* __restrict__ Wr1, const float* __restrict__ br1,
                           const float* __restrict__ mlp_W,
                           _Float16* __restrict__ WlWr1t, float* __restrict__ blr1,
                           _Float16* __restrict__ mlpWt) {
    int n = blockIdx.x, k = threadIdx.x;
    if (n < 512) {
        float v = (n < 256) ? Wl1[k*256 + n] : Wr1[k*256 + (n - 256)];
        WlWr1t[n*256 + k] = (_Float16)v;
        if (k == 0) blr1[n] = (n < 256) ? bl1[n] : br1[n - 256];
    } else {
        int nn = n - 512;
        mlpWt[nn*256 + k] = (_Float16)mlp_W[k*64 + nn];
    }
}

// ---------------- CSR by dst ----------------
__global__ void k_hist(const int* __restrict__ ei, int* __restrict__ counts) {
    int e = blockIdx.x*256 + threadIdx.x;
    if (e < EE) atomicAdd(&counts[ei[EE + e]], 1);
}

__global__ __launch_bounds__(1024) void k_scan(const int* __restrict__ counts,
                                               int* __restrict__ row_ptr, int* __restrict__ cursor) {
    __shared__ int part[1024];
    int t = threadIdx.x;
    const int per = (NN + 1023) / 1024;
    int b0 = t*per, b1 = min(b0 + per, NN);
    int s = 0;
    for (int i = b0; i < b1; ++i) s += counts[i];
    part[t] = s; __syncthreads();
    for (int d = 1; d < 1024; d <<= 1) {
        int v = (t >= d) ? part[t-d] : 0;
        __syncthreads();
        part[t] += v;
        __syncthreads();
    }
    int run = (t == 0) ? 0 : part[t-1];
    for (int i = b0; i < b1; ++i) { row_ptr[i] = run; cursor[i] = run; run += counts[i]; }
    if (t == 0) row_ptr[NN] = EE;
}

__global__ void k_scatter(const int* __restrict__ ei, int* __restrict__ cursor,
                          int* __restrict__ pos, int* __restrict__ csr_src,
                          int* __restrict__ dnode) {
    int e = blockIdx.x*256 + threadIdx.x;
    if (e < EE) {
        int d = ei[EE + e];
        int p = atomicAdd(&cursor[d], 1);
        pos[e] = p;
        csr_src[p] = ei[e];
        dnode[p] = d;
    }
}

// permute attr into CSR order (coalesced read, scattered 128B write), fp32->fp16,
// 64-wide with bias lane (k=63 -> 1.0)
__global__ void k_permattr(const float* __restrict__ attr, const int* __restrict__ pos,
                           _Float16* __restrict__ attr16) {
    int tid = threadIdx.x;
    int w = tid >> 6, lane = tid & 63;
    int e = blockIdx.x*4 + w;
    if (e >= EE) return;
    float v = (lane < 63) ? attr[(size_t)e*63 + lane] : 1.0f;
    attr16[(size_t)pos[e]*64 + lane] = (_Float16)v;
}

// ---------------- layer 0 xl/xr via folded K=5 (fp16 out) ----------------
__global__ void k_xlxr0(const float* __restrict__ x, const float* __restrict__ Acat,
                        _Float16* __restrict__ xlxr16) {
    int n = blockIdx.x, j = threadIdx.x;
    float a0 = Acat[5*512 + j], a1 = Acat[5*512 + 256 + j];
#pragma unroll
    for (int k = 0; k < 5; ++k) {
        float xv = x[n*5 + k];
        a0 += xv * Acat[k*512 + j];
        a1 += xv * Acat[k*512 + 256 + j];
    }
    xlxr16[(size_t)n*512 + j] = (_Float16)a0;
    xlxr16[(size_t)n*512 + 256 + j] = (_Float16)a1;
}

// ---------------- per-edge alpha, CSR-ordered: MFMA ee + register phase-B ----------------
// wave w = head w. one 64-edge chunk per block (grid = EE/64) for max TLP.
__global__ __launch_bounds__(256) void k_alpha3(const _Float16* __restrict__ attr16,
        const int* __restrict__ csrc, const int* __restrict__ dnode,
        const _Float16* __restrict__ Wpt, const float* __restrict__ att,
        const _Float16* __restrict__ xlxr16, float* __restrict__ alphaP) {
    int tid = threadIdx.x;
    int wave = tid >> 6, lane = tid & 63;
    int l15 = lane & 15, l4 = lane >> 4;

    // chunk-invariant: B-fragments (Wpt[col][k]) + att
    half8 bf[4][2];
    float attv[4];
#pragma unroll
    for (int ct = 0; ct < 4; ++ct) {
        int col = wave*64 + ct*16 + l15;
        attv[ct] = att[col];
#pragma unroll
        for (int ks = 0; ks < 2; ++ks)
            bf[ct][ks] = *(const half8*)&Wpt[(size_t)col*64 + ks*32 + l4*8];
    }

    int e0 = blockIdx.x * 64;
#pragma unroll
    for (int et = 0; et < 4; ++et) {
        int te = e0 + et*16;
        half8 a0 = *(const half8*)&attr16[(size_t)(te + l15)*64 + l4*8];
        half8 a1 = *(const half8*)&attr16[(size_t)(te + l15)*64 + 32 + l4*8];
        floatx4 acc[4];
#pragma unroll
        for (int ct = 0; ct < 4; ++ct) {
            floatx4 z = {};
            acc[ct] = __builtin_amdgcn_mfma_f32_16x16x32_f16(a0, bf[ct][0], z, 0, 0, 0);
            acc[ct] = __builtin_amdgcn_mfma_f32_16x16x32_f16(a1, bf[ct][1], acc[ct], 0, 0, 0);
        }
        int4 sv = *(const int4*)&csrc[te + l4*4];
        int4 dv = *(const int4*)&dnode[te + l4*4];
        int se[4] = {sv.x, sv.y, sv.z, sv.w};
        int de[4] = {dv.x, dv.y, dv.z, dv.w};
#pragma unroll
        for (int r = 0; r < 4; ++r) {
            const _Float16* xp = xlxr16 + (size_t)se[r]*512 + wave*64 + l15;
            const _Float16* rp = xlxr16 + (size_t)de[r]*512 + 256 + wave*64 + l15;
            float p = 0.f;
#pragma unroll
            for (int ct = 0; ct < 4; ++ct) {
                float m = acc[ct][r] + (float)xp[ct*16] + (float)rp[ct*16];
                float lr = (m > 0.f) ? m : 0.2f*m;
                p += lr * attv[ct];
            }
            p += __shfl_xor(p, 1);
            p += __shfl_xor(p, 2);
            p += __shfl_xor(p, 4);
            p += __shfl_xor(p, 8);
            if (l15 == 0) alphaP[(size_t)wave*EE + te + l4*4 + r] = p;
        }
    }
}

// ---------------- per-dst softmax + aggregate (fp16 gather) ----------------
__global__ __launch_bounds__(256) void k_agg(const float* __restrict__ alphaP,
                      const int* __restrict__ csr_src, const int* __restrict__ row_ptr,
                      const _Float16* __restrict__ xlxr16, const float* __restrict__ bias,
                      float* __restrict__ gat) {
    int n = blockIdx.x, j = threadIdx.x;
    int h = j >> 6, lane = j & 63;
    int s = row_ptr[n], e = row_ptr[n+1];
    if (e <= s) { gat[(size_t)n*256 + j] = bias[j]; return; }
    const float* ap = alphaP + (size_t)h*EE;
    float mx = -3.0e38f;
    for (int p = s + lane; p < e; p += 64) mx = fmaxf(mx, ap[p]);
#pragma unroll
    for (int m = 1; m < 64; m <<= 1) mx = fmaxf(mx, __shfl_xor(mx, m));
    float sm = 0.f;
    for (int p = s + lane; p < e; p += 64) sm += __expf(ap[p] - mx);
#pragma unroll
    for (int m = 1; m < 64; m <<= 1) sm += __shfl_xor(sm, m);
    float rden = 1.0f / sm;
    float acc = 0.f;
    int p = s;
    for (; p + 1 < e; p += 2) {
        float w0 = __expf(ap[p] - mx);
        float w1 = __expf(ap[p+1] - mx);
        float x0 = (float)xlxr16[(size_t)csr_src[p]*512 + j];
        float x1 = (float)xlxr16[(size_t)csr_src[p+1]*512 + j];
        acc += w0 * x0 + w1 * x1;
    }
    if (p < e) acc += __expf(ap[p] - mx) * (float)xlxr16[(size_t)csr_src[p]*512 + j];
    gat[(size_t)n*256 + j] = acc * rden + bias[j];
}

// ---------------- batchnorm ----------------
// 8-sharded stats to cut same-address atomic serialization
__global__ void k_bn_stats(const float* __restrict__ X, float* __restrict__ stats) {
    int j = threadIdx.x;
    int shard = blockIdx.x & 7;
    float s = 0.f, q = 0.f;
    for (int r = blockIdx.x; r < NN; r += gridDim.x) {
        float v = X[(size_t)r*256 + j];
        s += v; q += v*v;
    }
    atomicAdd(&stats[shard*512 + j], s);
    atomicAdd(&stats[shard*512 + 256 + j], q);
}

__global__ void k_bn_final(const float* __restrict__ stats, const float* __restrict__ gamma,
                           const float* __restrict__ beta, float* __restrict__ ss) {
    int j = threadIdx.x;
    float s = 0.f, q = 0.f;
#pragma unroll
    for (int sh = 0; sh < 8; ++sh) {
        s += stats[sh*512 + j];
        q += stats[sh*512 + 256 + j];
    }
    float mean = s * (1.0f/NN);
    float var  = q * (1.0f/NN) - mean*mean;
    float sc = rsqrtf(var + 1e-5f) * gamma[j];
    ss[j] = sc;
    ss[256 + j] = beta[j] - mean*sc;
}

__global__ void k_bn_apply(const float* __restrict__ X, const float* __restrict__ ss,
                           _Float16* __restrict__ Hh) {
    size_t i4 = (size_t)blockIdx.x*256 + threadIdx.x;   // one float4 per thread
    int col = (int)((i4*4) & 255);
    float4 v = *(const float4*)&X[i4*4];
    float4 sc = *(const float4*)&ss[col];
    float4 sh = *(const float4*)&ss[256 + col];
    half4 o;
    o[0] = (_Float16)fmaxf(v.x*sc.x + sh.x, 0.f);
    o[1] = (_Float16)fmaxf(v.y*sc.y + sh.y, 0.f);
    o[2] = (_Float16)fmaxf(v.z*sc.z + sh.z, 0.f);
    o[3] = (_Float16)fmaxf(v.w*sc.w + sh.w, 0.f);
    *(half4*)&Hh[i4*4] = o;
}

// ---------------- fp16 MFMA GEMM: C[M,cols] = A[M,K] @ Bt[N,K]^T + bias ----------------
template<bool RELU, typename OT>
__global__ __launch_bounds__(256) void k_gemm(const _Float16* __restrict__ A, const _Float16* __restrict__ Bt,
                       const float* __restrict__ bias, OT* __restrict__ C,
                       int M, int K, int ldc) {
    __shared__ __align__(16) _Float16 As[128][72];
    __shared__ __align__(16) _Float16 Bs[64][72];
    int tid = threadIdx.x;
    int wave = tid >> 6, lane = tid & 63;
    int l15 = lane & 15, l4 = lane >> 4;
    int row0 = blockIdx.x*128, n0 = blockIdx.y*64;
    floatx4 acc[2][4] = {};
    for (int k0 = 0; k0 < K; k0 += 64) {
#pragma unroll
        for (int q = 0; q < 4; ++q) {
            int c = tid + q*256;
            int r = c >> 3, kc = (c & 7)*8;
            int gr = row0 + r; if (gr >= M) gr = M - 1;
            *(half8*)&As[r][kc] = *(const half8*)&A[(size_t)gr*K + k0 + kc];
        }
#pragma unroll
        for (int q = 0; q < 2; ++q) {
            int c = tid + q*256;
            int r = c >> 3, kc = (c & 7)*8;
            *(half8*)&Bs[r][kc] = *(const half8*)&Bt[(size_t)(n0 + r)*K + k0 + kc];
        }
        __syncthreads();
#pragma unroll
        for (int ks = 0; ks < 64; ks += 32) {
            half8 a0 = *(const half8*)&As[wave*32 + l15][ks + l4*8];
            half8 a1 = *(const half8*)&As[wave*32 + 16 + l15][ks + l4*8];
#pragma unroll
            for (int nb = 0; nb < 4; ++nb) {
                half8 b = *(const half8*)&Bs[nb*16 + l15][ks + l4*8];
                acc[0][nb] = __builtin_amdgcn_mfma_f32_16x16x32_f16(a0, b, acc[0][nb], 0, 0, 0);
                acc[1][nb] = __builtin_amdgcn_mfma_f32_16x16x32_f16(a1, b, acc[1][nb], 0, 0, 0);
            }
        }
        __syncthreads();
    }
#pragma unroll
    for (int m = 0; m < 2; ++m)
#pragma unroll
    for (int nb = 0; nb < 4; ++nb) {
        int col = n0 + nb*16 + l15;
        float bv = bias[col];
#pragma unroll
        for (int r = 0; r < 4; ++r) {
            int grow = row0 + wave*32 + m*16 + l4*4 + r;
            if (grow < M) {
                float v = acc[m][nb][r] + bv;
                if (RELU) v = fmaxf(v, 0.f);
                C[(size_t)grow*ldc + col] = (OT)v;
            }
        }
    }
}

// ---------------- pooling (batch sorted -> contiguous ranges, no atomics) ----------------
__global__ void k_pool2(const float* __restrict__ mo, const int* __restrict__ batch,
                        float* __restrict__ pooledDiv) {
    int b = blockIdx.x;
    int j = threadIdx.x & 63, rg = threadIdx.x >> 6;
    int lo = 0, hi = NN;
    while (lo < hi) { int mid = (lo + hi) >> 1; if (batch[mid] < b) lo = mid + 1; else hi = mid; }
    int s = lo;
    lo = 0; hi = NN;
    while (lo < hi) { int mid = (lo + hi) >> 1; if (batch[mid] < b + 1) lo = mid + 1; else hi = mid; }
    int e = lo;
    float acc = 0.f;
    for (int r = s + rg; r < e; r += 4) acc += mo[(size_t)r*64 + j];
    __shared__ float red[256];
    red[threadIdx.x] = acc;
    __syncthreads();
    if (rg == 0) {
        float v = red[j] + red[64 + j] + red[128 + j] + red[192 + j];
        pooledDiv[b*64 + j] = v / fmaxf((float)(e - s), 1.f);
    }
}

__global__ void k_final(const float* __restrict__ pooledDiv,
                        const float* __restrict__ outW, const float* __restrict__ outb,
                        float* __restrict__ out) {
    int t = threadIdx.x;
    if (t >= 320) return;
    int b = t / 5, c = t % 5;
    float acc = outb[c];
    for (int k = 0; k < 64; ++k) acc += pooledDiv[b*64 + k] * outW[k*5 + c];
    out[t] = acc;
}

extern "C" void kernel_launch(void* const* d_in, const int* in_sizes, int n_in,
                              void* d_out, int out_size, void* d_ws, size_t ws_size,
                              hipStream_t stream) {
    const float* x      = (const float*)d_in[0];
    const int*   ei     = (const int*)d_in[1];
    const float* attr   = (const float*)d_in[2];
    const int*   batch  = (const int*)d_in[3];
    const float* node_W = (const float*)d_in[4];
    const float* node_b = (const float*)d_in[5];
    const float* edge_W = (const float*)d_in[6];
    const float* edge_b = (const float*)d_in[7];
    const float* Wl[2]   = {(const float*)d_in[8],  (const float*)d_in[17]};
    const float* bl[2]   = {(const float*)d_in[9],  (const float*)d_in[18]};
    const float* Wr[2]   = {(const float*)d_in[10], (const float*)d_in[19]};
    const float* br[2]   = {(const float*)d_in[11], (const float*)d_in[20]};
    const float* We[2]   = {(const float*)d_in[12], (const float*)d_in[21]};
    const float* att[2]  = {(const float*)d_in[13], (const float*)d_in[22]};
    const float* bias[2] = {(const float*)d_in[14], (const float*)d_in[23]};
    const float* gamma[2]= {(const float*)d_in[15], (const float*)d_in[24]};
    const float* beta[2] = {(const float*)d_in[16], (const float*)d_in[25]};
    const float* mlp_W = (const float*)d_in[26];
    const float* mlp_b = (const float*)d_in[27];
    const float* out_W = (const float*)d_in[28];
    const float* out_b = (const float*)d_in[29];
    float* out = (float*)d_out;

    char* p = (char*)d_ws;
    size_t off = 0;
    auto carve = [&](size_t bytes) -> void* {
        void* r = p + off;
        off = (off + bytes + 255) & ~(size_t)255;
        return r;
    };
    _Float16* Wpt0   = (_Float16*)carve(256*64*2);
    _Float16* Wpt1   = (_Float16*)carve(256*64*2);
    float*    Acat   = (float*)carve(6*512*4);
    _Float16* WlWr1t = (_Float16*)carve(512*256*2);
    float*    blr1   = (float*)carve(512*4);
    _Float16* mlpWt  = (_Float16*)carve(64*256*2);
    float*    ss     = (float*)carve(512*4);
    _Float16* xlxr16 = (_Float16*)carve((size_t)NN*512*2);
    float*    gat    = (float*)carve((size_t)NN*256*4);
    _Float16* h16    = (_Float16*)carve((size_t)NN*256*2);
    float*    alphaP = (float*)carve((size_t)EE*4*4);
    float*    mlo    = (float*)carve((size_t)NN*64*4);
    _Float16* attr16 = (_Float16*)carve((size_t)EE*64*2);
    int*      dnode  = (int*)carve((size_t)EE*4);
    int*      row_ptr= (int*)carve((NN+1)*4);
    int*      pos    = (int*)carve((size_t)EE*4);
    int*      csrc   = (int*)carve((size_t)EE*4);
    int*      cursor = (int*)carve(NN*4);
    float*    pooledDiv = (float*)carve(BB*64*4);
    char*     zz     = (char*)carve((NN + 8192)*4);
    int*      counts = (int*)zz;
    float*    stats  = (float*)(zz + (size_t)NN*4);   // 2 layers x 8 shards x 512
    if (off > ws_size) return;  // workspace too small: bail (output stays wrong -> visible signal)

    hipMemsetAsync(zz, 0, (size_t)(NN + 8192)*4, stream);
    k_prep_edgeW<<<dim3(64,2), 256, 0, stream>>>(edge_W, edge_b, We[0], We[1], Wpt0, Wpt1);
    k_prep_acat<<<6, 512, 0, stream>>>(node_W, node_b, Wl[0], bl[0], Wr[0], br[0], Acat);
    k_prep_t16<<<576, 256, 0, stream>>>(Wl[1], bl[1], Wr[1], br[1], mlp_W, WlWr1t, blr1, mlpWt);
    k_hist<<<(EE+255)/256, 256, 0, stream>>>(ei, counts);
    k_scan<<<1, 1024, 0, stream>>>(counts, row_ptr, cursor);
    k_scatter<<<(EE+255)/256, 256, 0, stream>>>(ei, cursor, pos, csrc, dnode);
    k_permattr<<<EE/4, 256, 0, stream>>>(attr, pos, attr16);
    k_xlxr0<<<NN, 256, 0, stream>>>(x, Acat, xlxr16);

    for (int L = 0; L < 2; ++L) {
        k_alpha3<<<EE/64, 256, 0, stream>>>(attr16, csrc, dnode, L ? Wpt1 : Wpt0, att[L], xlxr16, alphaP);
        k_agg<<<NN, 256, 0, stream>>>(alphaP, csrc, row_ptr, xlxr16, bias[L], gat);
        k_bn_stats<<<256, 256, 0, stream>>>(gat, stats + L*4096);
        k_bn_final<<<1, 256, 0, stream>>>(stats + L*4096, gamma[L], beta[L], ss);
        k_bn_apply<<<NN*256/4/256, 256, 0, stream>>>(gat, ss, h16);
        if (L == 0)
            k_gemm<false, _Float16><<<dim3(157, 8), 256, 0, stream>>>(h16, WlWr1t, blr1, xlxr16, NN, 256, 512);
        else
            k_gemm<true, float><<<dim3(157, 1), 256, 0, stream>>>(h16, mlpWt, mlp_b, mlo, NN, 256, 64);
    }
    k_pool2<<<BB, 256, 0, stream>>>(mlo, batch, pooledDiv);
    k_final<<<1, 320, 0, stream>>>(pooledDiv, out_W, out_b, out);
}

// Round 6
// 459.165 us; speedup vs baseline: 2.5555x; 1.1670x over previous
//
#include <hip/hip_runtime.h>

#define NN 20000
#define EE 320000
#define BB 64

typedef _Float16 half8 __attribute__((ext_vector_type(8)));
typedef _Float16 half4 __attribute__((ext_vector_type(4)));
typedef float floatx4 __attribute__((ext_vector_type(4)));

// ---------------- prep: weight folding ----------------
__global__ void k_prep_edgeW(const float* __restrict__ edge_W, const float* __restrict__ edge_b,
                             const float* __restrict__ We0, const float* __restrict__ We1,
                             _Float16* __restrict__ Wpt0, _Float16* __restrict__ Wpt1) {
    __shared__ float row[256];
    int k = blockIdx.x, layer = blockIdx.y, j = threadIdx.x;
    row[j] = (k < 63) ? edge_W[k*256 + j] : edge_b[j];
    __syncthreads();
    const float* We = layer ? We1 : We0;
    float acc = 0.f;
    for (int t = 0; t < 256; ++t) acc += row[t] * We[t*256 + j];
    (layer ? Wpt1 : Wpt0)[j*64 + k] = (_Float16)acc;   // transposed [col][k] fp16
}

__global__ void k_prep_acat(const float* __restrict__ node_W, const float* __restrict__ node_b,
                            const float* __restrict__ Wl0, const float* __restrict__ bl0,
                            const float* __restrict__ Wr0, const float* __restrict__ br0,
                            float* __restrict__ Acat) {
    __shared__ float row[256];
    int k = blockIdx.x, j = threadIdx.x;
    if (j < 256) row[j] = (k < 5) ? node_W[k*256 + j] : node_b[j];
    __syncthreads();
    int jj = j & 255;
    const float* W = (j < 256) ? Wl0 : Wr0;
    float acc = 0.f;
    for (int t = 0; t < 256; ++t) acc += row[t] * W[t*256 + jj];
    if (k == 5) acc += (j < 256) ? bl0[jj] : br0[jj];
    Acat[k*512 + j] = acc;
}

__global__ void k_prep_t16(const float* __restrict__ Wl1, const float* __restrict__ bl1,
                           const float* __restrict__ Wr1, const float* __restrict__ br1,
                           const float* __restrict__ mlp_W,
                           _Float16* __restrict__ WlWr1t, float* __restrict__ blr1,
                           _Float16* __restrict__ mlpWt) {
    int n = blockIdx.x, k = threadIdx.x;
    if (n < 512) {
        float v = (n < 256) ? Wl1[k*256 + n] : Wr1[k*256 + (n - 256)];
        WlWr1t[n*256 + k] = (_Float16)v;
        if (k == 0) blr1[n] = (n < 256) ? bl1[n] : br1[n - 256];
    } else {
        int nn = n - 512;
        mlpWt[nn*256 + k] = (_Float16)mlp_W[k*64 + nn];
    }
}

// ---------------- CSR by dst ----------------
__global__ void k_hist(const int* __restrict__ ei, int* __restrict__ counts) {
    int e = blockIdx.x*256 + threadIdx.x;
    if (e < EE) atomicAdd(&counts[ei[EE + e]], 1);
}

__global__ __launch_bounds__(1024) void k_scan(const int* __restrict__ counts,
                                               int* __restrict__ row_ptr, int* __restrict__ cursor) {
    __shared__ int part[1024];
    int t = threadIdx.x;
    const int per = (NN + 1023) / 1024;
    int b0 = t*per, b1 = min(b0 + per, NN);
    int s = 0;
    for (int i = b0; i < b1; ++i) s += counts[i];
    part[t] = s; __syncthreads();
    for (int d = 1; d < 1024; d <<= 1) {
        int v = (t >= d) ? part[t-d] : 0;
        __syncthreads();
        part[t] += v;
        __syncthreads();
    }
    int run = (t == 0) ? 0 : part[t-1];
    for (int i = b0; i < b1; ++i) { row_ptr[i] = run; cursor[i] = run; run += counts[i]; }
    if (t == 0) row_ptr[NN] = EE;
}

__global__ void k_scatter(const int* __restrict__ ei, int* __restrict__ cursor,
                          int* __restrict__ pos, int* __restrict__ csr_src) {
    int e = blockIdx.x*256 + threadIdx.x;
    if (e < EE) {
        int d = ei[EE + e];
        int p = atomicAdd(&cursor[d], 1);
        pos[e] = p;
        csr_src[p] = ei[e];
    }
}

// permute attr into CSR order (coalesced read, scattered 128B write), fp32->fp16,
// 64-wide with bias lane (k=63 -> 1.0)
__global__ void k_permattr(const float* __restrict__ attr, const int* __restrict__ pos,
                           _Float16* __restrict__ attr16) {
    int tid = threadIdx.x;
    int w = tid >> 6, lane = tid & 63;
    int e = blockIdx.x*4 + w;
    if (e >= EE) return;
    float v = (lane < 63) ? attr[(size_t)e*63 + lane] : 1.0f;
    attr16[(size_t)pos[e]*64 + lane] = (_Float16)v;
}

// ---------------- layer 0 xl/xr via folded K=5 (fp16 out) ----------------
__global__ void k_xlxr0(const float* __restrict__ x, const float* __restrict__ Acat,
                        _Float16* __restrict__ xlxr16) {
    int n = blockIdx.x, j = threadIdx.x;
    float a0 = Acat[5*512 + j], a1 = Acat[5*512 + 256 + j];
#pragma unroll
    for (int k = 0; k < 5; ++k) {
        float xv = x[n*5 + k];
        a0 += xv * Acat[k*512 + j];
        a1 += xv * Acat[k*512 + 256 + j];
    }
    xlxr16[(size_t)n*512 + j] = (_Float16)a0;
    xlxr16[(size_t)n*512 + 256 + j] = (_Float16)a1;
}

// ---------------- fused GATv2 layer: alpha (MFMA ee) + online softmax + aggregate ----------
// 4 dst nodes per block; wave w = head w. LDS xl tile shared by alpha and aggregate phases.
#define NPB 4
__global__ __launch_bounds__(256) void k_fused(const _Float16* __restrict__ attr16,
        const int* __restrict__ csrc, const int* __restrict__ row_ptr,
        const _Float16* __restrict__ Wpt, const float* __restrict__ att,
        const _Float16* __restrict__ xlxr16, const float* __restrict__ bias,
        float* __restrict__ gat) {
    int tid = threadIdx.x;
    int wave = tid >> 6, lane = tid & 63;
    int l15 = lane & 15, l4 = lane >> 4;
    int col = wave*64 + lane;                 // this lane's output column

    __shared__ __align__(16) _Float16 xls[16][256];  // xl rows of the current 16-edge tile

    // block-invariant: B fragments (Wpt) + att
    half8 bf[4][2];
    float attv[4];
#pragma unroll
    for (int ct = 0; ct < 4; ++ct) {
        int c = wave*64 + ct*16 + l15;
        attv[ct] = att[c];
        bf[ct][0] = *(const half8*)&Wpt[(size_t)c*64 + l4*8];
        bf[ct][1] = *(const half8*)&Wpt[(size_t)c*64 + 32 + l4*8];
    }
    float bv = bias[col];

    for (int i = 0; i < NPB; ++i) {
        int n = blockIdx.x*NPB + i;
        if (n >= NN) break;
        int s = row_ptr[n], e = row_ptr[n+1];
        if (e <= s) { gat[(size_t)n*256 + col] = bv; continue; }

        // per-node: xr_n fragment (cols wave*64 + ct*16 + l15)
        float xrf[4];
#pragma unroll
        for (int ct = 0; ct < 4; ++ct)
            xrf[ct] = (float)xlxr16[(size_t)n*512 + 256 + wave*64 + ct*16 + l15];

        float m_run = -3.0e38f, l_run = 0.f, out_acc = 0.f;
        for (int t0 = s; t0 < e; t0 += 16) {
            int nt = min(16, e - t0);
            // stage xl rows (thread t: row t>>4, 16 cols at (t&15)*16)
            {
                int r = tid >> 4, c0 = (tid & 15) * 16;
                int er = t0 + ((r < nt) ? r : 0);
                const _Float16* src = &xlxr16[(size_t)csrc[er]*512 + c0];
                *(half8*)&xls[r][c0]     = *(const half8*)&src[0];
                *(half8*)&xls[r][c0 + 8] = *(const half8*)&src[8];
            }
            __syncthreads();
            // A fragments from attr16 (CSR rows t0+l15, clamped)
            size_t ar = (size_t)(t0 + ((l15 < nt) ? l15 : 0)) * 64;
            half8 a0 = *(const half8*)&attr16[ar + l4*8];
            half8 a1 = *(const half8*)&attr16[ar + 32 + l4*8];
            floatx4 acc[4];
#pragma unroll
            for (int ct = 0; ct < 4; ++ct) {
                floatx4 z = {};
                acc[ct] = __builtin_amdgcn_mfma_f32_16x16x32_f16(a0, bf[ct][0], z, 0, 0, 0);
                acc[ct] = __builtin_amdgcn_mfma_f32_16x16x32_f16(a1, bf[ct][1], acc[ct], 0, 0, 0);
            }
            // alpha for edges l4*4+r (quarter-local), keep all 4 in regs
            float p[4];
#pragma unroll
            for (int r = 0; r < 4; ++r) {
                int eidx = l4*4 + r;
                float pv = 0.f;
#pragma unroll
                for (int ct = 0; ct < 4; ++ct) {
                    float m = acc[ct][r] + (float)xls[eidx][wave*64 + ct*16 + l15] + xrf[ct];
                    float lr = (m > 0.f) ? m : 0.2f*m;
                    pv += lr * attv[ct];
                }
                pv += __shfl_xor(pv, 1);
                pv += __shfl_xor(pv, 2);
                pv += __shfl_xor(pv, 4);
                pv += __shfl_xor(pv, 8);
                p[r] = (eidx < nt) ? pv : -3.0e38f;
            }
            // broadcast all 16 alphas to every lane of the wave
            float aall[16];
#pragma unroll
            for (int k = 0; k < 16; ++k)
                aall[k] = __shfl(p[k & 3], (k >> 2) << 4);
            // online softmax update + accumulate out of LDS tile
            float mt = aall[0];
#pragma unroll
            for (int k = 1; k < 16; ++k) mt = fmaxf(mt, aall[k]);
            float mnew = fmaxf(m_run, mt);
            float scale = __expf(m_run - mnew);
            out_acc *= scale; l_run *= scale;
#pragma unroll
            for (int k = 0; k < 16; ++k) {
                float wk = __expf(aall[k] - mnew);
                l_run += wk;
                out_acc += wk * (float)xls[k][col];
            }
            m_run = mnew;
            __syncthreads();
        }
        gat[(size_t)n*256 + col] = out_acc / l_run + bv;
    }
}

// ---------------- batchnorm ----------------
// 16-sharded stats, 1024 blocks
__global__ void k_bn_stats(const float* __restrict__ X, float* __restrict__ stats) {
    int j = threadIdx.x;
    int shard = blockIdx.x & 15;
    float s = 0.f, q = 0.f;
    for (int r = blockIdx.x; r < NN; r += gridDim.x) {
        float v = X[(size_t)r*256 + j];
        s += v; q += v*v;
    }
    atomicAdd(&stats[shard*512 + j], s);
    atomicAdd(&stats[shard*512 + 256 + j], q);
}

__global__ void k_bn_final(const float* __restrict__ stats, const float* __restrict__ gamma,
                           const float* __restrict__ beta, float* __restrict__ ss) {
    int j = threadIdx.x;
    float s = 0.f, q = 0.f;
#pragma unroll
    for (int sh = 0; sh < 16; ++sh) {
        s += stats[sh*512 + j];
        q += stats[sh*512 + 256 + j];
    }
    float mean = s * (1.0f/NN);
    float var  = q * (1.0f/NN) - mean*mean;
    float sc = rsqrtf(var + 1e-5f) * gamma[j];
    ss[j] = sc;
    ss[256 + j] = beta[j] - mean*sc;
}

__global__ void k_bn_apply(const float* __restrict__ X, const float* __restrict__ ss,
                           _Float16* __restrict__ Hh) {
    size_t i4 = (size_t)blockIdx.x*256 + threadIdx.x;   // one float4 per thread
    int col = (int)((i4*4) & 255);
    float4 v = *(const float4*)&X[i4*4];
    float4 sc = *(const float4*)&ss[col];
    float4 sh = *(const float4*)&ss[256 + col];
    half4 o;
    o[0] = (_Float16)fmaxf(v.x*sc.x + sh.x, 0.f);
    o[1] = (_Float16)fmaxf(v.y*sc.y + sh.y, 0.f);
    o[2] = (_Float16)fmaxf(v.z*sc.z + sh.z, 0.f);
    o[3] = (_Float16)fmaxf(v.w*sc.w + sh.w, 0.f);
    *(half4*)&Hh[i4*4] = o;
}

// ---------------- fp16 MFMA GEMM: C[M,cols] = A[M,K] @ Bt[N,K]^T + bias ----------------
template<bool RELU, typename OT>
__global__ __launch_bounds__(256) void k_gemm(const _Float16* __restrict__ A, const _Float16* __restrict__ Bt,
                       const float* __restrict__ bias, OT* __restrict__ C,
                       int M, int K, int ldc) {
    __shared__ __align__(16) _Float16 As[128][72];
    __shared__ __align__(16) _Float16 Bs[64][72];
    int tid = threadIdx.x;
    int wave = tid >> 6, lane = tid & 63;
    int l15 = lane & 15, l4 = lane >> 4;
    int row0 = blockIdx.x*128, n0 = blockIdx.y*64;
    floatx4 acc[2][4] = {};
    for (int k0 = 0; k0 < K; k0 += 64) {
#pragma unroll
        for (int q = 0; q < 4; ++q) {
            int c = tid + q*256;
            int r = c >> 3, kc = (c & 7)*8;
            int gr = row0 + r; if (gr >= M) gr = M - 1;
            *(half8*)&As[r][kc] = *(const half8*)&A[(size_t)gr*K + k0 + kc];
        }
#pragma unroll
        for (int q = 0; q < 2; ++q) {
            int c = tid + q*256;
            int r = c >> 3, kc = (c & 7)*8;
            *(half8*)&Bs[r][kc] = *(const half8*)&Bt[(size_t)(n0 + r)*K + k0 + kc];
        }
        __syncthreads();
#pragma unroll
        for (int ks = 0; ks < 64; ks += 32) {
            half8 a0 = *(const half8*)&As[wave*32 + l15][ks + l4*8];
            half8 a1 = *(const half8*)&As[wave*32 + 16 + l15][ks + l4*8];
#pragma unroll
            for (int nb = 0; nb < 4; ++nb) {
                half8 b = *(const half8*)&Bs[nb*16 + l15][ks + l4*8];
                acc[0][nb] = __builtin_amdgcn_mfma_f32_16x16x32_f16(a0, b, acc[0][nb], 0, 0, 0);
                acc[1][nb] = __builtin_amdgcn_mfma_f32_16x16x32_f16(a1, b, acc[1][nb], 0, 0, 0);
            }
        }
        __syncthreads();
    }
#pragma unroll
    for (int m = 0; m < 2; ++m)
#pragma unroll
    for (int nb = 0; nb < 4; ++nb) {
        int col = n0 + nb*16 + l15;
        float bv = bias[col];
#pragma unroll
        for (int r = 0; r < 4; ++r) {
            int grow = row0 + wave*32 + m*16 + l4*4 + r;
            if (grow < M) {
                float v = acc[m][nb][r] + bv;
                if (RELU) v = fmaxf(v, 0.f);
                C[(size_t)grow*ldc + col] = (OT)v;
            }
        }
    }
}

// ---------------- pooling (batch sorted -> contiguous ranges, no atomics) ----------------
__global__ void k_pool2(const float* __restrict__ mo, const int* __restrict__ batch,
                        float* __restrict__ pooledDiv) {
    int b = blockIdx.x;
    int j = threadIdx.x & 63, rg = threadIdx.x >> 6;
    int lo = 0, hi = NN;
    while (lo < hi) { int mid = (lo + hi) >> 1; if (batch[mid] < b) lo = mid + 1; else hi = mid; }
    int s = lo;
    lo = 0; hi = NN;
    while (lo < hi) { int mid = (lo + hi) >> 1; if (batch[mid] < b + 1) lo = mid + 1; else hi = mid; }
    int e = lo;
    float acc = 0.f;
    for (int r = s + rg; r < e; r += 4) acc += mo[(size_t)r*64 + j];
    __shared__ float red[256];
    red[threadIdx.x] = acc;
    __syncthreads();
    if (rg == 0) {
        float v = red[j] + red[64 + j] + red[128 + j] + red[192 + j];
        pooledDiv[b*64 + j] = v / fmaxf((float)(e - s), 1.f);
    }
}

__global__ void k_final(const float* __restrict__ pooledDiv,
                        const float* __restrict__ outW, const float* __restrict__ outb,
                        float* __restrict__ out) {
    int t = threadIdx.x;
    if (t >= 320) return;
    int b = t / 5, c = t % 5;
    float acc = outb[c];
    for (int k = 0; k < 64; ++k) acc += pooledDiv[b*64 + k] * outW[k*5 + c];
    out[t] = acc;
}

extern "C" void kernel_launch(void* const* d_in, const int* in_sizes, int n_in,
                              void* d_out, int out_size, void* d_ws, size_t ws_size,
                              hipStream_t stream) {
    const float* x      = (const float*)d_in[0];
    const int*   ei     = (const int*)d_in[1];
    const float* attr   = (const float*)d_in[2];
    const int*   batch  = (const int*)d_in[3];
    const float* node_W = (const float*)d_in[4];
    const float* node_b = (const float*)d_in[5];
    const float* edge_W = (const float*)d_in[6];
    const float* edge_b = (const float*)d_in[7];
    const float* Wl[2]   = {(const float*)d_in[8],  (const float*)d_in[17]};
    const float* bl[2]   = {(const float*)d_in[9],  (const float*)d_in[18]};
    const float* Wr[2]   = {(const float*)d_in[10], (const float*)d_in[19]};
    const float* br[2]   = {(const float*)d_in[11], (const float*)d_in[20]};
    const float* We[2]   = {(const float*)d_in[12], (const float*)d_in[21]};
    const float* att[2]  = {(const float*)d_in[13], (const float*)d_in[22]};
    const float* bias[2] = {(const float*)d_in[14], (const float*)d_in[23]};
    const float* gamma[2]= {(const float*)d_in[15], (const float*)d_in[24]};
    const float* beta[2] = {(const float*)d_in[16], (const float*)d_in[25]};
    const float* mlp_W = (const float*)d_in[26];
    const float* mlp_b = (const float*)d_in[27];
    const float* out_W = (const float*)d_in[28];
    const float* out_b = (const float*)d_in[29];
    float* out = (float*)d_out;

    char* p = (char*)d_ws;
    size_t off = 0;
    auto carve = [&](size_t bytes) -> void* {
        void* r = p + off;
        off = (off + bytes + 255) & ~(size_t)255;
        return r;
    };
    _Float16* Wpt0   = (_Float16*)carve(256*64*2);
    _Float16* Wpt1   = (_Float16*)carve(256*64*2);
    float*    Acat   = (float*)carve(6*512*4);
    _Float16* WlWr1t = (_Float16*)carve(512*256*2);
    float*    blr1   = (float*)carve(512*4);
    _Float16* mlpWt  = (_Float16*)carve(64*256*2);
    float*    ss     = (float*)carve(512*4);
    _Float16* xlxr16 = (_Float16*)carve((size_t)NN*512*2);
    float*    gat    = (float*)carve((size_t)NN*256*4);
    _Float16* h16    = (_Float16*)carve((size_t)NN*256*2);
    float*    mlo    = (float*)carve((size_t)NN*64*4);
    _Float16* attr16 = (_Float16*)carve((size_t)EE*64*2);
    int*      row_ptr= (int*)carve((NN+1)*4);
    int*      pos    = (int*)carve((size_t)EE*4);
    int*      csrc   = (int*)carve((size_t)EE*4);
    int*      cursor = (int*)carve(NN*4);
    float*    pooledDiv = (float*)carve(BB*64*4);
    char*     zz     = (char*)carve((NN + 16384)*4);
    int*      counts = (int*)zz;
    float*    stats  = (float*)(zz + (size_t)NN*4);   // 2 layers x 16 shards x 512
    if (off > ws_size) return;  // workspace too small: bail (output stays wrong -> visible signal)

    hipMemsetAsync(zz, 0, (size_t)(NN + 16384)*4, stream);
    k_prep_edgeW<<<dim3(64,2), 256, 0, stream>>>(edge_W, edge_b, We[0], We[1], Wpt0, Wpt1);
    k_prep_acat<<<6, 512, 0, stream>>>(node_W, node_b, Wl[0], bl[0], Wr[0], br[0], Acat);
    k_prep_t16<<<576, 256, 0, stream>>>(Wl[1], bl[1], Wr[1], br[1], mlp_W, WlWr1t, blr1, mlpWt);
    k_hist<<<(EE+255)/256, 256, 0, stream>>>(ei, counts);
    k_scan<<<1, 1024, 0, stream>>>(counts, row_ptr, cursor);
    k_scatter<<<(EE+255)/256, 256, 0, stream>>>(ei, cursor, pos, csrc);
    k_permattr<<<EE/4, 256, 0, stream>>>(attr, pos, attr16);
    k_xlxr0<<<NN, 256, 0, stream>>>(x, Acat, xlxr16);

    for (int L = 0; L < 2; ++L) {
        k_fused<<<(NN + NPB - 1)/NPB, 256, 0, stream>>>(attr16, csrc, row_ptr,
                 L ? Wpt1 : Wpt0, att[L], xlxr16, bias[L], gat);
        k_bn_stats<<<1024, 256, 0, stream>>>(gat, stats + L*8192);
        k_bn_final<<<1, 256, 0, stream>>>(stats + L*8192, gamma[L], beta[L], ss);
        k_bn_apply<<<NN*256/4/256, 256, 0, stream>>>(gat, ss, h16);
        if (L == 0)
            k_gemm<false, _Float16><<<dim3(157, 8), 256, 0, stream>>>(h16, WlWr1t, blr1, xlxr16, NN, 256, 512);
        else
            k_gemm<true, float><<<dim3(157, 1), 256, 0, stream>>>(h16, mlpWt, mlp_b, mlo, NN, 256, 64);
    }
    k_pool2<<<BB, 256, 0, stream>>>(mlo, batch, pooledDiv);
    k_final<<<1, 320, 0, stream>>>(pooledDiv, out_W, out_b, out);
}